// Round 4
// baseline (947.532 us; speedup 1.0000x reference)
//
#include <hip/hip_runtime.h>
#include <hip/hip_fp16.h>

#define BLK 256
#define NB 2000      // buckets; NB*BW == 200000
#define BW 100       // nodes per bucket (dst_local fits 7 bits)
#define CHUNK 32768  // edges per binning block (run length ~16 edges/bucket = 64B)

// ---------- bucket build ----------

__global__ void k_zero_i(int* __restrict__ p, int n) {
  int i = blockIdx.x * blockDim.x + threadIdx.x;
  if (i < n) p[i] = 0;
}

__global__ void k_hist_buckets(const int* __restrict__ dst, int e, int* __restrict__ gcnt) {
  __shared__ int h[NB];
  for (int i = threadIdx.x; i < NB; i += BLK) h[i] = 0;
  __syncthreads();
  int base = blockIdx.x * CHUNK;
  for (int k = 0; k < CHUNK; k += BLK) {
    int i = base + k + threadIdx.x;
    if (i < e) atomicAdd(&h[dst[i] / BW], 1);
  }
  __syncthreads();
  for (int b = threadIdx.x; b < NB; b += BLK) {
    int c = h[b];
    if (c) atomicAdd(&gcnt[b], c);
  }
}

// scan of gcnt[NB] -> gbase[NB+1], init gcursor. 1024 threads, 2 elems each.
__global__ void k_scan_buckets(const int* __restrict__ gcnt, int* __restrict__ gbase,
                               int* __restrict__ gcursor, int e) {
  __shared__ int s[1024];
  int t = threadIdx.x;
  int i0 = 2 * t, i1 = 2 * t + 1;
  int a = (i0 < NB) ? gcnt[i0] : 0;
  int b = (i1 < NB) ? gcnt[i1] : 0;
  int ps = a + b;
  s[t] = ps;
  __syncthreads();
  for (int d = 1; d < 1024; d <<= 1) {
    int u = (t >= d) ? s[t - d] : 0;
    __syncthreads();
    s[t] += u;
    __syncthreads();
  }
  int ex = s[t] - ps;
  if (i0 < NB) { gbase[i0] = ex; gcursor[i0] = ex; }
  if (i1 < NB) { gbase[i1] = ex + a; gcursor[i1] = ex + a; }
  if (t == 0) gbase[NB] = e;
}

// bin edges: pack src(18b) | dst_local(7b)<<18
__global__ void k_bin(const int* __restrict__ src, const int* __restrict__ dst, int e,
                      int* __restrict__ gcursor, unsigned* __restrict__ binned) {
  __shared__ int lcnt[NB];
  __shared__ int lbase[NB];
  int t = threadIdx.x;
  for (int i = t; i < NB; i += BLK) lcnt[i] = 0;
  __syncthreads();
  int base = blockIdx.x * CHUNK;
  for (int k = 0; k < CHUNK; k += BLK) {
    int i = base + k + t;
    if (i < e) atomicAdd(&lcnt[dst[i] / BW], 1);
  }
  __syncthreads();
  for (int b = t; b < NB; b += BLK) {
    int c = lcnt[b];
    lbase[b] = c ? atomicAdd(&gcursor[b], c) : 0;
    lcnt[b] = 0;
  }
  __syncthreads();
  for (int k = 0; k < CHUNK; k += BLK) {
    int i = base + k + t;
    if (i < e) {
      int d = dst[i];
      int b = d / BW;
      int dl = d - b * BW;
      int pos = atomicAdd(&lcnt[b], 1);
      binned[lbase[b] + pos] = (unsigned)src[i] | ((unsigned)dl << 18);
    }
  }
}

// per-bucket degree -> dinv
__global__ void k_ldeg(const unsigned* __restrict__ binned, const int* __restrict__ gbase,
                       float* __restrict__ dinv) {
  __shared__ int cnt[BW];
  int t = threadIdx.x;
  if (t < BW) cnt[t] = 0;
  __syncthreads();
  int b = blockIdx.x;
  int p0 = gbase[b], p1 = gbase[b + 1];
  for (int p = p0 + t; p < p1; p += BLK) atomicAdd(&cnt[binned[p] >> 18], 1);
  __syncthreads();
  if (t < BW) dinv[b * BW + t] = rsqrtf((float)cnt[t] + 1.0f);
}

// ---------- layer math ----------

// hs1h = fp16( (x @ W1) * dinv )
__global__ void k_transform1(const float* __restrict__ x, const float* __restrict__ W1,
                             const float* __restrict__ dinv, __half* __restrict__ hs1h, int n) {
  __shared__ float w[160];
  int t = threadIdx.x;
  if (t < 160) w[t] = W1[t];
  __syncthreads();
  int i = blockIdx.x * blockDim.x + t;
  if (i >= n) return;
  float xi[10];
#pragma unroll
  for (int k = 0; k < 10; k++) xi[k] = x[i * 10 + k];
  float di = dinv[i];
  __half2 hv[8];
#pragma unroll
  for (int j = 0; j < 8; j++) {
    float acc0 = 0.f, acc1 = 0.f;
#pragma unroll
    for (int k = 0; k < 10; k++) {
      acc0 = fmaf(xi[k], w[k * 16 + 2 * j], acc0);
      acc1 = fmaf(xi[k], w[k * 16 + 2 * j + 1], acc1);
    }
    hv[j] = __floats2half2_rn(acc0 * di, acc1 * di);
  }
  float4* o = (float4*)(hs1h + (size_t)i * 16);
  o[0] = *(float4*)&hv[0];
  o[1] = *(float4*)&hv[4];
}

// one block per bucket: LDS-accumulate layer-1, fuse layer-2 transform.
// 2 lanes per edge; each lane handles 8 features (16B fp16 gather).
__global__ void __launch_bounds__(BLK) k_agg1(const unsigned* __restrict__ binned,
                                              const int* __restrict__ gbase,
                                              const __half* __restrict__ hs1h,
                                              const float* __restrict__ dinv,
                                              const float* __restrict__ b1,
                                              const float* __restrict__ W2,
                                              float* __restrict__ hs2) {
  __shared__ float agg[BW * 16];   // 6.4 KB
  __shared__ float w2[32];
  __shared__ float sb1[16];
  int t = threadIdx.x;
  if (t < 32) w2[t] = W2[t];
  if (t < 16) sb1[t] = b1[t];
  for (int i = t; i < BW * 16; i += BLK) agg[i] = 0.f;
  __syncthreads();
  int bkt = blockIdx.x;
  int p0 = gbase[bkt], p1 = gbase[bkt + 1];
  const int c = t & 1;            // feature half (8 feats)
  const int stride = BLK / 2;     // 128 edges per block-iter
  int p = p0 + (t >> 1);

#define GATHER(pk, R)  { int s_ = (pk) & 0x3FFFF; \
    R = *(const float4*)(hs1h + (size_t)s_ * 16 + c * 8); }
#define ACCUM(pk, R)   { int dl_ = (pk) >> 18; \
    const __half2* hp_ = (const __half2*)&R; \
    float* a_ = agg + dl_ * 16 + c * 8; \
    float2 f0_ = __half22float2(hp_[0]); \
    float2 f1_ = __half22float2(hp_[1]); \
    float2 f2_ = __half22float2(hp_[2]); \
    float2 f3_ = __half22float2(hp_[3]); \
    atomicAdd(a_ + 0, f0_.x); atomicAdd(a_ + 1, f0_.y); \
    atomicAdd(a_ + 2, f1_.x); atomicAdd(a_ + 3, f1_.y); \
    atomicAdd(a_ + 4, f2_.x); atomicAdd(a_ + 5, f2_.y); \
    atomicAdd(a_ + 6, f3_.x); atomicAdd(a_ + 7, f3_.y); }

  for (; p + 3 * stride < p1; p += 4 * stride) {
    unsigned pk0 = binned[p];
    unsigned pk1 = binned[p + stride];
    unsigned pk2 = binned[p + 2 * stride];
    unsigned pk3 = binned[p + 3 * stride];
    float4 r0, r1, r2, r3;
    GATHER(pk0, r0); GATHER(pk1, r1); GATHER(pk2, r2); GATHER(pk3, r3);
    ACCUM(pk0, r0); ACCUM(pk1, r1); ACCUM(pk2, r2); ACCUM(pk3, r3);
  }
  for (; p < p1; p += stride) {
    unsigned pk = binned[p];
    float4 r;
    GATHER(pk, r);
    ACCUM(pk, r);
  }
#undef GATHER
#undef ACCUM
  __syncthreads();
  if (t < BW) {
    int v = bkt * BW + t;
    float di = dinv[v];
    float h0 = 0.f, h1 = 0.f;
    const __half* selfp = hs1h + (size_t)v * 16;
#pragma unroll
    for (int j = 0; j < 16; j++) {
      float sum = agg[t * 16 + j] + __half2float(selfp[j]);
      float a = fmaxf(fmaf(di, sum, sb1[j]), 0.f);
      h0 = fmaf(a, w2[j * 2 + 0], h0);
      h1 = fmaf(a, w2[j * 2 + 1], h1);
    }
    hs2[(size_t)v * 2 + 0] = h0 * di;
    hs2[(size_t)v * 2 + 1] = h1 * di;
  }
}

// one block per bucket: layer-2 aggregate + output. hs2 is 1.6 MB -> L2-resident.
__global__ void k_agg2(const unsigned* __restrict__ binned, const int* __restrict__ gbase,
                       const float* __restrict__ hs2, const float* __restrict__ dinv,
                       const float* __restrict__ b2, float* __restrict__ out) {
  __shared__ float agg[BW * 2];
  int t = threadIdx.x;
  if (t < BW * 2) agg[t] = 0.f;
  __syncthreads();
  int bkt = blockIdx.x;
  int p0 = gbase[bkt], p1 = gbase[bkt + 1];
  int p = p0 + t;

#define ACC2(pk, M) { int dl_ = (pk) >> 18; \
    atomicAdd(&agg[dl_ * 2 + 0], M.x); atomicAdd(&agg[dl_ * 2 + 1], M.y); }

  for (; p + 3 * BLK < p1; p += 4 * BLK) {
    unsigned pk0 = binned[p];
    unsigned pk1 = binned[p + BLK];
    unsigned pk2 = binned[p + 2 * BLK];
    unsigned pk3 = binned[p + 3 * BLK];
    float2 m0 = *(const float2*)(hs2 + (size_t)(pk0 & 0x3FFFF) * 2);
    float2 m1 = *(const float2*)(hs2 + (size_t)(pk1 & 0x3FFFF) * 2);
    float2 m2 = *(const float2*)(hs2 + (size_t)(pk2 & 0x3FFFF) * 2);
    float2 m3 = *(const float2*)(hs2 + (size_t)(pk3 & 0x3FFFF) * 2);
    ACC2(pk0, m0); ACC2(pk1, m1); ACC2(pk2, m2); ACC2(pk3, m3);
  }
  for (; p < p1; p += BLK) {
    unsigned pk = binned[p];
    float2 m = *(const float2*)(hs2 + (size_t)(pk & 0x3FFFF) * 2);
    ACC2(pk, m);
  }
#undef ACC2
  __syncthreads();
  if (t < BW) {
    int v = bkt * BW + t;
    float di = dinv[v];
    out[(size_t)v * 2 + 0] = fmaf(di, agg[t * 2 + 0] + hs2[(size_t)v * 2 + 0], b2[0]);
    out[(size_t)v * 2 + 1] = fmaf(di, agg[t * 2 + 1] + hs2[(size_t)v * 2 + 1], b2[1]);
  }
}

extern "C" void kernel_launch(void* const* d_in, const int* in_sizes, int n_in,
                              void* d_out, int out_size, void* d_ws, size_t ws_size,
                              hipStream_t stream) {
  const float* x  = (const float*)d_in[0];
  const int*   ei = (const int*)d_in[1];
  const float* W1 = (const float*)d_in[2];
  const float* b1 = (const float*)d_in[3];
  const float* W2 = (const float*)d_in[4];
  const float* b2 = (const float*)d_in[5];
  float* out = (float*)d_out;

  const int n = in_sizes[0] / 10;   // 200000
  const int e = in_sizes[1] / 2;    // 6400000
  const int* src = ei;
  const int* dst = ei + e;

  // workspace layout
  char* ws = (char*)d_ws;
  int*      gcnt    = (int*)ws;      ws += (size_t)NB * 4;
  int*      gbase   = (int*)ws;      ws += ((size_t)NB + 1) * 4;
  int*      gcursor = (int*)ws;      ws += (size_t)NB * 4;
  unsigned* binned  = (unsigned*)ws; ws += (size_t)e * 4;
  float*    dinv    = (float*)ws;    ws += (size_t)n * 4;
  __half*   hs1h    = (__half*)ws;   ws += (size_t)n * 16 * 2;
  float*    hs2     = (float*)ws;    ws += (size_t)n * 2 * 4;

  int gN = (n + BLK - 1) / BLK;
  int gC = (e + CHUNK - 1) / CHUNK;   // 196 binning blocks

  k_zero_i<<<(NB + BLK - 1) / BLK, BLK, 0, stream>>>(gcnt, NB);
  k_hist_buckets<<<gC, BLK, 0, stream>>>(dst, e, gcnt);
  k_scan_buckets<<<1, 1024, 0, stream>>>(gcnt, gbase, gcursor, e);
  k_bin<<<gC, BLK, 0, stream>>>(src, dst, e, gcursor, binned);
  k_ldeg<<<NB, BLK, 0, stream>>>(binned, gbase, dinv);
  k_transform1<<<gN, BLK, 0, stream>>>(x, W1, dinv, hs1h, n);
  k_agg1<<<NB, BLK, 0, stream>>>(binned, gbase, hs1h, dinv, b1, W2, hs2);
  k_agg2<<<NB, BLK, 0, stream>>>(binned, gbase, hs2, dinv, b2, out);
}

// Round 6
// 941.608 us; speedup vs baseline: 1.0063x; 1.0063x over previous
//
#include <hip/hip_runtime.h>
#include <hip/hip_fp16.h>

#define BLK 256
#define NB 2000      // buckets; NB*BW == 200000
#define BW 100       // nodes per bucket (dst_local fits 7 bits)
#define CHUNK 32768  // edges per binning block (run length ~16 edges/bucket = 64B)

// ---------- bucket build ----------

__global__ void k_zero_i(int* __restrict__ p, int n) {
  int i = blockIdx.x * blockDim.x + threadIdx.x;
  if (i < n) p[i] = 0;
}

__global__ void k_hist_buckets(const int* __restrict__ dst, int e, int* __restrict__ gcnt) {
  __shared__ int h[NB];
  for (int i = threadIdx.x; i < NB; i += BLK) h[i] = 0;
  __syncthreads();
  int base = blockIdx.x * CHUNK;
  for (int k = 0; k < CHUNK; k += BLK) {
    int i = base + k + threadIdx.x;
    if (i < e) atomicAdd(&h[dst[i] / BW], 1);
  }
  __syncthreads();
  for (int b = threadIdx.x; b < NB; b += BLK) {
    int c = h[b];
    if (c) atomicAdd(&gcnt[b], c);
  }
}

// scan of gcnt[NB] -> gbase[NB+1], init gcursor. 1024 threads, 2 elems each.
__global__ void k_scan_buckets(const int* __restrict__ gcnt, int* __restrict__ gbase,
                               int* __restrict__ gcursor, int e) {
  __shared__ int s[1024];
  int t = threadIdx.x;
  int i0 = 2 * t, i1 = 2 * t + 1;
  int a = (i0 < NB) ? gcnt[i0] : 0;
  int b = (i1 < NB) ? gcnt[i1] : 0;
  int ps = a + b;
  s[t] = ps;
  __syncthreads();
  for (int d = 1; d < 1024; d <<= 1) {
    int u = (t >= d) ? s[t - d] : 0;
    __syncthreads();
    s[t] += u;
    __syncthreads();
  }
  int ex = s[t] - ps;
  if (i0 < NB) { gbase[i0] = ex; gcursor[i0] = ex; }
  if (i1 < NB) { gbase[i1] = ex + a; gcursor[i1] = ex + a; }
  if (t == 0) gbase[NB] = e;
}

// bin edges: pack src(18b) | dst_local(7b)<<18
__global__ void k_bin(const int* __restrict__ src, const int* __restrict__ dst, int e,
                      int* __restrict__ gcursor, unsigned* __restrict__ binned) {
  __shared__ int lcnt[NB];
  __shared__ int lbase[NB];
  int t = threadIdx.x;
  for (int i = t; i < NB; i += BLK) lcnt[i] = 0;
  __syncthreads();
  int base = blockIdx.x * CHUNK;
  for (int k = 0; k < CHUNK; k += BLK) {
    int i = base + k + t;
    if (i < e) atomicAdd(&lcnt[dst[i] / BW], 1);
  }
  __syncthreads();
  for (int b = t; b < NB; b += BLK) {
    int c = lcnt[b];
    lbase[b] = c ? atomicAdd(&gcursor[b], c) : 0;
    lcnt[b] = 0;
  }
  __syncthreads();
  for (int k = 0; k < CHUNK; k += BLK) {
    int i = base + k + t;
    if (i < e) {
      int d = dst[i];
      int b = d / BW;
      int dl = d - b * BW;
      int pos = atomicAdd(&lcnt[b], 1);
      binned[lbase[b] + pos] = (unsigned)src[i] | ((unsigned)dl << 18);
    }
  }
}

// per-bucket degree -> dinv
__global__ void k_ldeg(const unsigned* __restrict__ binned, const int* __restrict__ gbase,
                       float* __restrict__ dinv) {
  __shared__ int cnt[BW];
  int t = threadIdx.x;
  if (t < BW) cnt[t] = 0;
  __syncthreads();
  int b = blockIdx.x;
  int p0 = gbase[b], p1 = gbase[b + 1];
  for (int p = p0 + t; p < p1; p += BLK) atomicAdd(&cnt[binned[p] >> 18], 1);
  __syncthreads();
  if (t < BW) dinv[b * BW + t] = rsqrtf((float)cnt[t] + 1.0f);
}

// ---------- layer math ----------

// hs1 = (x @ W1) * dinv, feature-split into lo (feats 0-7) and hi (feats 8-15),
// each N x 8 fp16 = 3.2 MB (fits per-XCD 4 MiB L2)
__global__ void k_transform1(const float* __restrict__ x, const float* __restrict__ W1,
                             const float* __restrict__ dinv,
                             __half* __restrict__ hs1_lo, __half* __restrict__ hs1_hi, int n) {
  __shared__ float w[160];
  int t = threadIdx.x;
  if (t < 160) w[t] = W1[t];
  __syncthreads();
  int i = blockIdx.x * blockDim.x + t;
  if (i >= n) return;
  float xi[10];
#pragma unroll
  for (int k = 0; k < 10; k++) xi[k] = x[i * 10 + k];
  float di = dinv[i];
  __half2 hv[8];
#pragma unroll
  for (int j = 0; j < 8; j++) {
    float acc0 = 0.f, acc1 = 0.f;
#pragma unroll
    for (int k = 0; k < 10; k++) {
      acc0 = fmaf(xi[k], w[k * 16 + 2 * j], acc0);
      acc1 = fmaf(xi[k], w[k * 16 + 2 * j + 1], acc1);
    }
    hv[j] = __floats2half2_rn(acc0 * di, acc1 * di);
  }
  *(float4*)(hs1_lo + (size_t)i * 8) = *(float4*)&hv[0];
  *(float4*)(hs1_hi + (size_t)i * 8) = *(float4*)&hv[4];
}

// accumulate one feature-half: 1 lane per edge, 16B gather from a 3.2MB L2-resident table,
// LDS agg padded to stride 9 (banks (9*dl+j)%32 spread; stride 16 hit only 2 banks)
#define ACC8(pk, R) { int dl_ = (pk) >> 18; \
    const __half2* hp_ = (const __half2*)&R; \
    float* a_ = agg + dl_ * 9; \
    float2 f0_ = __half22float2(hp_[0]); \
    float2 f1_ = __half22float2(hp_[1]); \
    float2 f2_ = __half22float2(hp_[2]); \
    float2 f3_ = __half22float2(hp_[3]); \
    atomicAdd(a_ + 0, f0_.x); atomicAdd(a_ + 1, f0_.y); \
    atomicAdd(a_ + 2, f1_.x); atomicAdd(a_ + 3, f1_.y); \
    atomicAdd(a_ + 4, f2_.x); atomicAdd(a_ + 5, f2_.y); \
    atomicAdd(a_ + 6, f3_.x); atomicAdd(a_ + 7, f3_.y); }

__global__ void __launch_bounds__(BLK) k_agg1_lo(const unsigned* __restrict__ binned,
                                                 const int* __restrict__ gbase,
                                                 const __half* __restrict__ hs1_lo,
                                                 float* __restrict__ agg_lo) {
  __shared__ float agg[BW * 9];
  int t = threadIdx.x;
  for (int i = t; i < BW * 9; i += BLK) agg[i] = 0.f;
  __syncthreads();
  int bkt = blockIdx.x;
  int p0 = gbase[bkt], p1 = gbase[bkt + 1];
  int p = p0 + t;
  for (; p + 3 * BLK < p1; p += 4 * BLK) {
    unsigned pk0 = binned[p];
    unsigned pk1 = binned[p + BLK];
    unsigned pk2 = binned[p + 2 * BLK];
    unsigned pk3 = binned[p + 3 * BLK];
    float4 r0 = *(const float4*)(hs1_lo + (size_t)(pk0 & 0x3FFFF) * 8);
    float4 r1 = *(const float4*)(hs1_lo + (size_t)(pk1 & 0x3FFFF) * 8);
    float4 r2 = *(const float4*)(hs1_lo + (size_t)(pk2 & 0x3FFFF) * 8);
    float4 r3 = *(const float4*)(hs1_lo + (size_t)(pk3 & 0x3FFFF) * 8);
    ACC8(pk0, r0); ACC8(pk1, r1); ACC8(pk2, r2); ACC8(pk3, r3);
  }
  for (; p < p1; p += BLK) {
    unsigned pk = binned[p];
    float4 r = *(const float4*)(hs1_lo + (size_t)(pk & 0x3FFFF) * 8);
    ACC8(pk, r);
  }
  __syncthreads();
  for (int i = t; i < BW * 8; i += BLK)
    agg_lo[(size_t)bkt * BW * 8 + i] = agg[(i >> 3) * 9 + (i & 7)];
}

// hi half + epilogue: combine agg_lo (global) + agg_hi (LDS) + self term, fuse layer 2
__global__ void __launch_bounds__(BLK) k_agg1_hi(const unsigned* __restrict__ binned,
                                                 const int* __restrict__ gbase,
                                                 const __half* __restrict__ hs1_lo,
                                                 const __half* __restrict__ hs1_hi,
                                                 const float* __restrict__ agg_lo,
                                                 const float* __restrict__ dinv,
                                                 const float* __restrict__ b1,
                                                 const float* __restrict__ W2,
                                                 float* __restrict__ hs2) {
  __shared__ float agg[BW * 9];
  __shared__ float w2[32];
  __shared__ float sb1[16];
  int t = threadIdx.x;
  if (t < 32) w2[t] = W2[t];
  if (t < 16) sb1[t] = b1[t];
  for (int i = t; i < BW * 9; i += BLK) agg[i] = 0.f;
  __syncthreads();
  int bkt = blockIdx.x;
  int p0 = gbase[bkt], p1 = gbase[bkt + 1];
  int p = p0 + t;
  for (; p + 3 * BLK < p1; p += 4 * BLK) {
    unsigned pk0 = binned[p];
    unsigned pk1 = binned[p + BLK];
    unsigned pk2 = binned[p + 2 * BLK];
    unsigned pk3 = binned[p + 3 * BLK];
    float4 r0 = *(const float4*)(hs1_hi + (size_t)(pk0 & 0x3FFFF) * 8);
    float4 r1 = *(const float4*)(hs1_hi + (size_t)(pk1 & 0x3FFFF) * 8);
    float4 r2 = *(const float4*)(hs1_hi + (size_t)(pk2 & 0x3FFFF) * 8);
    float4 r3 = *(const float4*)(hs1_hi + (size_t)(pk3 & 0x3FFFF) * 8);
    ACC8(pk0, r0); ACC8(pk1, r1); ACC8(pk2, r2); ACC8(pk3, r3);
  }
  for (; p < p1; p += BLK) {
    unsigned pk = binned[p];
    float4 r = *(const float4*)(hs1_hi + (size_t)(pk & 0x3FFFF) * 8);
    ACC8(pk, r);
  }
  __syncthreads();
  if (t < BW) {
    int v = bkt * BW + t;
    float di = dinv[v];
    float h0 = 0.f, h1 = 0.f;
    const __half* slo = hs1_lo + (size_t)v * 8;
    const __half* shi = hs1_hi + (size_t)v * 8;
    const float* alo = agg_lo + (size_t)bkt * BW * 8 + t * 8;
#pragma unroll
    for (int j = 0; j < 8; j++) {
      float sum = alo[j] + __half2float(slo[j]);
      float a = fmaxf(fmaf(di, sum, sb1[j]), 0.f);
      h0 = fmaf(a, w2[j * 2 + 0], h0);
      h1 = fmaf(a, w2[j * 2 + 1], h1);
    }
#pragma unroll
    for (int j = 0; j < 8; j++) {
      float sum = agg[t * 9 + j] + __half2float(shi[j]);
      float a = fmaxf(fmaf(di, sum, sb1[8 + j]), 0.f);
      h0 = fmaf(a, w2[(8 + j) * 2 + 0], h0);
      h1 = fmaf(a, w2[(8 + j) * 2 + 1], h1);
    }
    hs2[(size_t)v * 2 + 0] = h0 * di;
    hs2[(size_t)v * 2 + 1] = h1 * di;
  }
}
#undef ACC8

// layer-2 aggregate + output. hs2 is 1.6 MB -> per-XCD L2-resident. LDS pad stride 3.
__global__ void k_agg2(const unsigned* __restrict__ binned, const int* __restrict__ gbase,
                       const float* __restrict__ hs2, const float* __restrict__ dinv,
                       const float* __restrict__ b2, float* __restrict__ out) {
  __shared__ float agg[BW * 3];
  int t = threadIdx.x;
  for (int i = t; i < BW * 3; i += BLK) agg[i] = 0.f;   // FIX: 300 > 256, must loop
  __syncthreads();
  int bkt = blockIdx.x;
  int p0 = gbase[bkt], p1 = gbase[bkt + 1];
  int p = p0 + t;
#define ACC2(pk, M) { int dl_ = (pk) >> 18; \
    atomicAdd(&agg[dl_ * 3 + 0], M.x); atomicAdd(&agg[dl_ * 3 + 1], M.y); }
  for (; p + 3 * BLK < p1; p += 4 * BLK) {
    unsigned pk0 = binned[p];
    unsigned pk1 = binned[p + BLK];
    unsigned pk2 = binned[p + 2 * BLK];
    unsigned pk3 = binned[p + 3 * BLK];
    float2 m0 = *(const float2*)(hs2 + (size_t)(pk0 & 0x3FFFF) * 2);
    float2 m1 = *(const float2*)(hs2 + (size_t)(pk1 & 0x3FFFF) * 2);
    float2 m2 = *(const float2*)(hs2 + (size_t)(pk2 & 0x3FFFF) * 2);
    float2 m3 = *(const float2*)(hs2 + (size_t)(pk3 & 0x3FFFF) * 2);
    ACC2(pk0, m0); ACC2(pk1, m1); ACC2(pk2, m2); ACC2(pk3, m3);
  }
  for (; p < p1; p += BLK) {
    unsigned pk = binned[p];
    float2 m = *(const float2*)(hs2 + (size_t)(pk & 0x3FFFF) * 2);
    ACC2(pk, m);
  }
#undef ACC2
  __syncthreads();
  if (t < BW) {
    int v = bkt * BW + t;
    float di = dinv[v];
    out[(size_t)v * 2 + 0] = fmaf(di, agg[t * 3 + 0] + hs2[(size_t)v * 2 + 0], b2[0]);
    out[(size_t)v * 2 + 1] = fmaf(di, agg[t * 3 + 1] + hs2[(size_t)v * 2 + 1], b2[1]);
  }
}

extern "C" void kernel_launch(void* const* d_in, const int* in_sizes, int n_in,
                              void* d_out, int out_size, void* d_ws, size_t ws_size,
                              hipStream_t stream) {
  const float* x  = (const float*)d_in[0];
  const int*   ei = (const int*)d_in[1];
  const float* W1 = (const float*)d_in[2];
  const float* b1 = (const float*)d_in[3];
  const float* W2 = (const float*)d_in[4];
  const float* b2 = (const float*)d_in[5];
  float* out = (float*)d_out;

  const int n = in_sizes[0] / 10;   // 200000
  const int e = in_sizes[1] / 2;    // 6400000
  const int* src = ei;
  const int* dst = ei + e;

  // workspace layout
  char* ws = (char*)d_ws;
  int*      gcnt    = (int*)ws;      ws += (size_t)NB * 4;
  int*      gbase   = (int*)ws;      ws += ((size_t)NB + 1) * 4;
  int*      gcursor = (int*)ws;      ws += (size_t)NB * 4;
  unsigned* binned  = (unsigned*)ws; ws += (size_t)e * 4;
  float*    dinv    = (float*)ws;    ws += (size_t)n * 4;
  __half*   hs1_lo  = (__half*)ws;   ws += (size_t)n * 8 * 2;
  __half*   hs1_hi  = (__half*)ws;   ws += (size_t)n * 8 * 2;
  float*    agg_lo  = (float*)ws;    ws += (size_t)n * 8 * 4;
  float*    hs2     = (float*)ws;    ws += (size_t)n * 2 * 4;

  int gN = (n + BLK - 1) / BLK;
  int gC = (e + CHUNK - 1) / CHUNK;   // 196 binning blocks

  k_zero_i<<<(NB + BLK - 1) / BLK, BLK, 0, stream>>>(gcnt, NB);
  k_hist_buckets<<<gC, BLK, 0, stream>>>(dst, e, gcnt);
  k_scan_buckets<<<1, 1024, 0, stream>>>(gcnt, gbase, gcursor, e);
  k_bin<<<gC, BLK, 0, stream>>>(src, dst, e, gcursor, binned);
  k_ldeg<<<NB, BLK, 0, stream>>>(binned, gbase, dinv);
  k_transform1<<<gN, BLK, 0, stream>>>(x, W1, dinv, hs1_lo, hs1_hi, n);
  k_agg1_lo<<<NB, BLK, 0, stream>>>(binned, gbase, hs1_lo, agg_lo);
  k_agg1_hi<<<NB, BLK, 0, stream>>>(binned, gbase, hs1_lo, hs1_hi, agg_lo, dinv, b1, W2, hs2);
  k_agg2<<<NB, BLK, 0, stream>>>(binned, gbase, hs2, dinv, b2, out);
}

// Round 7
// 922.013 us; speedup vs baseline: 1.0277x; 1.0213x over previous
//
#include <hip/hip_runtime.h>
#include <hip/hip_fp16.h>

#define BLK 256
#define NB 2000              // dst buckets; NB*BW == 200000
#define BW 100               // nodes per bucket (dst_local fits 7 bits)
#define NBINS (NB * 2)       // bin = dst_bucket*2 + src_half
#define CHUNK 32768          // edges per binning block

// ---------- bin build ----------

__global__ void k_zero_i(int* __restrict__ p, int n) {
  int i = blockIdx.x * blockDim.x + threadIdx.x;
  if (i < n) p[i] = 0;
}

__global__ void k_hist(const int* __restrict__ src, const int* __restrict__ dst,
                       int e, int half, int* __restrict__ gcnt) {
  __shared__ int h[NBINS];
  for (int i = threadIdx.x; i < NBINS; i += BLK) h[i] = 0;
  __syncthreads();
  int base = blockIdx.x * CHUNK;
  for (int k = 0; k < CHUNK; k += BLK) {
    int i = base + k + threadIdx.x;
    if (i < e) {
      int b = (dst[i] / BW) * 2 + (src[i] >= half ? 1 : 0);
      atomicAdd(&h[b], 1);
    }
  }
  __syncthreads();
  for (int b = threadIdx.x; b < NBINS; b += BLK) {
    int c = h[b];
    if (c) atomicAdd(&gcnt[b], c);
  }
}

// exclusive scan of gcnt[NBINS] -> gbase[NBINS+1]; 1024 threads, 4 elems each
__global__ void k_scan(const int* __restrict__ gcnt, int* __restrict__ gbase,
                       int* __restrict__ gcur, int e) {
  __shared__ int s[1024];
  int t = threadIdx.x;
  int i = 4 * t;
  int v0 = (i + 0 < NBINS) ? gcnt[i + 0] : 0;
  int v1 = (i + 1 < NBINS) ? gcnt[i + 1] : 0;
  int v2 = (i + 2 < NBINS) ? gcnt[i + 2] : 0;
  int v3 = (i + 3 < NBINS) ? gcnt[i + 3] : 0;
  int sum = v0 + v1 + v2 + v3;
  s[t] = sum;
  __syncthreads();
  for (int d = 1; d < 1024; d <<= 1) {
    int u = (t >= d) ? s[t - d] : 0;
    __syncthreads();
    s[t] += u;
    __syncthreads();
  }
  int ex = s[t] - sum;
  if (i + 0 < NBINS) { gbase[i + 0] = ex;             gcur[i + 0] = ex; }
  if (i + 1 < NBINS) { gbase[i + 1] = ex + v0;        gcur[i + 1] = ex + v0; }
  if (i + 2 < NBINS) { gbase[i + 2] = ex + v0 + v1;   gcur[i + 2] = ex + v0 + v1; }
  if (i + 3 < NBINS) { gbase[i + 3] = ex + v0 + v1 + v2; gcur[i + 3] = ex + v0 + v1 + v2; }
  if (t == 0) gbase[NBINS] = e;
}

// bin edges: pack src(18b) | dst_local(7b)<<18
__global__ void k_bin(const int* __restrict__ src, const int* __restrict__ dst,
                      int e, int half, int* __restrict__ gcur, unsigned* __restrict__ binned) {
  __shared__ int lcnt[NBINS];
  __shared__ int lbase[NBINS];
  int t = threadIdx.x;
  for (int i = t; i < NBINS; i += BLK) lcnt[i] = 0;
  __syncthreads();
  int base = blockIdx.x * CHUNK;
  for (int k = 0; k < CHUNK; k += BLK) {
    int i = base + k + t;
    if (i < e) {
      int b = (dst[i] / BW) * 2 + (src[i] >= half ? 1 : 0);
      atomicAdd(&lcnt[b], 1);
    }
  }
  __syncthreads();
  for (int b = t; b < NBINS; b += BLK) {
    int c = lcnt[b];
    lbase[b] = c ? atomicAdd(&gcur[b], c) : 0;
    lcnt[b] = 0;
  }
  __syncthreads();
  for (int k = 0; k < CHUNK; k += BLK) {
    int i = base + k + t;
    if (i < e) {
      int s = src[i];
      int d = dst[i];
      int db = d / BW;
      int b = db * 2 + (s >= half ? 1 : 0);
      int dl = d - db * BW;
      int pos = atomicAdd(&lcnt[b], 1);
      binned[lbase[b] + pos] = (unsigned)s | ((unsigned)dl << 18);
    }
  }
}

// per-bucket degree -> dinv (reads both src-halves: contiguous range)
__global__ void k_ldeg(const unsigned* __restrict__ binned, const int* __restrict__ gbase,
                       float* __restrict__ dinv) {
  __shared__ int cnt[BW];
  int t = threadIdx.x;
  if (t < BW) cnt[t] = 0;
  __syncthreads();
  int b = blockIdx.x;
  int p0 = gbase[2 * b], p1 = gbase[2 * b + 2];
  for (int p = p0 + t; p < p1; p += BLK) atomicAdd(&cnt[binned[p] >> 18], 1);
  __syncthreads();
  if (t < BW) dinv[b * BW + t] = rsqrtf((float)cnt[t] + 1.0f);
}

// ---------- layer math ----------

// hs1 = fp16( (x @ W1) * dinv ), full 16-feature row (32B, one cache line)
__global__ void k_transform1(const float* __restrict__ x, const float* __restrict__ W1,
                             const float* __restrict__ dinv, __half* __restrict__ hs1, int n) {
  __shared__ float w[160];
  int t = threadIdx.x;
  if (t < 160) w[t] = W1[t];
  __syncthreads();
  int i = blockIdx.x * blockDim.x + t;
  if (i >= n) return;
  float xi[10];
#pragma unroll
  for (int k = 0; k < 10; k++) xi[k] = x[i * 10 + k];
  float di = dinv[i];
  __half2 hv[8];
#pragma unroll
  for (int j = 0; j < 8; j++) {
    float acc0 = 0.f, acc1 = 0.f;
#pragma unroll
    for (int k = 0; k < 10; k++) {
      acc0 = fmaf(xi[k], w[k * 16 + 2 * j], acc0);
      acc1 = fmaf(xi[k], w[k * 16 + 2 * j + 1], acc1);
    }
    hv[j] = __floats2half2_rn(acc0 * di, acc1 * di);
  }
  float4* o = (float4*)(hs1 + (size_t)i * 16);
  o[0] = *(float4*)&hv[0];
  o[1] = *(float4*)&hv[4];
}

// accumulate full 16-feature row into LDS (stride 17 pad)
#define ACC16(pk, RA, RB) { int dl_ = (pk) >> 18; \
    float* a_ = agg + dl_ * 17; \
    const __half2* ha_ = (const __half2*)&RA; \
    const __half2* hb_ = (const __half2*)&RB; \
    _Pragma("unroll") \
    for (int q_ = 0; q_ < 4; q_++) { \
      float2 fa_ = __half22float2(ha_[q_]); \
      float2 fb_ = __half22float2(hb_[q_]); \
      atomicAdd(a_ + 2 * q_ + 0, fa_.x); atomicAdd(a_ + 2 * q_ + 1, fa_.y); \
      atomicAdd(a_ + 8 + 2 * q_ + 0, fb_.x); atomicAdd(a_ + 8 + 2 * q_ + 1, fb_.y); \
    } }

#define EDGE_LOOP(P0, P1, TBL) \
  int p = (P0) + t; \
  for (; p + 3 * BLK < (P1); p += 4 * BLK) { \
    unsigned pk0 = binned[p]; \
    unsigned pk1 = binned[p + BLK]; \
    unsigned pk2 = binned[p + 2 * BLK]; \
    unsigned pk3 = binned[p + 3 * BLK]; \
    const float4* rp0 = (const float4*)(TBL + (size_t)(pk0 & 0x3FFFF) * 16); \
    const float4* rp1 = (const float4*)(TBL + (size_t)(pk1 & 0x3FFFF) * 16); \
    const float4* rp2 = (const float4*)(TBL + (size_t)(pk2 & 0x3FFFF) * 16); \
    const float4* rp3 = (const float4*)(TBL + (size_t)(pk3 & 0x3FFFF) * 16); \
    float4 a0 = rp0[0], b0 = rp0[1]; \
    float4 a1 = rp1[0], b1v = rp1[1]; \
    float4 a2 = rp2[0], b2v = rp2[1]; \
    float4 a3 = rp3[0], b3 = rp3[1]; \
    ACC16(pk0, a0, b0); ACC16(pk1, a1, b1v); ACC16(pk2, a2, b2v); ACC16(pk3, a3, b3); \
  } \
  for (; p < (P1); p += BLK) { \
    unsigned pk = binned[p]; \
    const float4* rp = (const float4*)(TBL + (size_t)(pk & 0x3FFFF) * 16); \
    float4 ra = rp[0], rb = rp[1]; \
    ACC16(pk, ra, rb); \
  }

// src-half A: gathers stay within hs1[0 .. half*16) = 3.2 MB (per-XCD L2-resident)
__global__ void __launch_bounds__(BLK) k_agg1A(const unsigned* __restrict__ binned,
                                               const int* __restrict__ gbase,
                                               const __half* __restrict__ hs1,
                                               __half* __restrict__ aggp) {
  __shared__ float agg[BW * 17];
  int t = threadIdx.x;
  for (int i = t; i < BW * 17; i += BLK) agg[i] = 0.f;
  __syncthreads();
  int bkt = blockIdx.x;
  int p0 = gbase[2 * bkt], p1 = gbase[2 * bkt + 1];
  EDGE_LOOP(p0, p1, hs1)
  __syncthreads();
  for (int i = t; i < BW * 16; i += BLK)
    aggp[(size_t)bkt * (BW * 16) + i] = __float2half(agg[(i >> 4) * 17 + (i & 15)]);
}

// src-half B: gathers within hs1[half*16 ..) = 3.2 MB; epilogue combines + fused layer 2
__global__ void __launch_bounds__(BLK) k_agg1B(const unsigned* __restrict__ binned,
                                               const int* __restrict__ gbase,
                                               const __half* __restrict__ hs1,
                                               const __half* __restrict__ aggp,
                                               const float* __restrict__ dinv,
                                               const float* __restrict__ b1,
                                               const float* __restrict__ W2,
                                               float* __restrict__ hs2) {
  __shared__ float agg[BW * 17];
  __shared__ float w2[32];
  __shared__ float sb1[16];
  int t = threadIdx.x;
  if (t < 32) w2[t] = W2[t];
  if (t < 16) sb1[t] = b1[t];
  for (int i = t; i < BW * 17; i += BLK) agg[i] = 0.f;
  __syncthreads();
  int bkt = blockIdx.x;
  int p0 = gbase[2 * bkt + 1], p1 = gbase[2 * bkt + 2];
  EDGE_LOOP(p0, p1, hs1)
  __syncthreads();
  if (t < BW) {
    int v = bkt * BW + t;
    float di = dinv[v];
    float h0 = 0.f, h1 = 0.f;
    const __half* ap = aggp + (size_t)bkt * (BW * 16) + t * 16;
    const __half* sp = hs1 + (size_t)v * 16;
#pragma unroll
    for (int j = 0; j < 16; j++) {
      float sum = agg[t * 17 + j] + __half2float(ap[j]) + __half2float(sp[j]);
      float a = fmaxf(fmaf(di, sum, sb1[j]), 0.f);
      h0 = fmaf(a, w2[j * 2 + 0], h0);
      h1 = fmaf(a, w2[j * 2 + 1], h1);
    }
    hs2[(size_t)v * 2 + 0] = h0 * di;
    hs2[(size_t)v * 2 + 1] = h1 * di;
  }
}
#undef EDGE_LOOP
#undef ACC16

// layer-2 aggregate + output; hs2 = 1.6 MB, L2-resident. Edges: full bucket range.
__global__ void k_agg2(const unsigned* __restrict__ binned, const int* __restrict__ gbase,
                       const float* __restrict__ hs2, const float* __restrict__ dinv,
                       const float* __restrict__ b2, float* __restrict__ out) {
  __shared__ float agg[BW * 3];
  int t = threadIdx.x;
  for (int i = t; i < BW * 3; i += BLK) agg[i] = 0.f;
  __syncthreads();
  int bkt = blockIdx.x;
  int p0 = gbase[2 * bkt], p1 = gbase[2 * bkt + 2];
  int p = p0 + t;
#define ACC2(pk, M) { int dl_ = (pk) >> 18; \
    atomicAdd(&agg[dl_ * 3 + 0], M.x); atomicAdd(&agg[dl_ * 3 + 1], M.y); }
  for (; p + 3 * BLK < p1; p += 4 * BLK) {
    unsigned pk0 = binned[p];
    unsigned pk1 = binned[p + BLK];
    unsigned pk2 = binned[p + 2 * BLK];
    unsigned pk3 = binned[p + 3 * BLK];
    float2 m0 = *(const float2*)(hs2 + (size_t)(pk0 & 0x3FFFF) * 2);
    float2 m1 = *(const float2*)(hs2 + (size_t)(pk1 & 0x3FFFF) * 2);
    float2 m2 = *(const float2*)(hs2 + (size_t)(pk2 & 0x3FFFF) * 2);
    float2 m3 = *(const float2*)(hs2 + (size_t)(pk3 & 0x3FFFF) * 2);
    ACC2(pk0, m0); ACC2(pk1, m1); ACC2(pk2, m2); ACC2(pk3, m3);
  }
  for (; p < p1; p += BLK) {
    unsigned pk = binned[p];
    float2 m = *(const float2*)(hs2 + (size_t)(pk & 0x3FFFF) * 2);
    ACC2(pk, m);
  }
#undef ACC2
  __syncthreads();
  if (t < BW) {
    int v = bkt * BW + t;
    float di = dinv[v];
    out[(size_t)v * 2 + 0] = fmaf(di, agg[t * 3 + 0] + hs2[(size_t)v * 2 + 0], b2[0]);
    out[(size_t)v * 2 + 1] = fmaf(di, agg[t * 3 + 1] + hs2[(size_t)v * 2 + 1], b2[1]);
  }
}

extern "C" void kernel_launch(void* const* d_in, const int* in_sizes, int n_in,
                              void* d_out, int out_size, void* d_ws, size_t ws_size,
                              hipStream_t stream) {
  const float* x  = (const float*)d_in[0];
  const int*   ei = (const int*)d_in[1];
  const float* W1 = (const float*)d_in[2];
  const float* b1 = (const float*)d_in[3];
  const float* W2 = (const float*)d_in[4];
  const float* b2 = (const float*)d_in[5];
  float* out = (float*)d_out;

  const int n = in_sizes[0] / 10;   // 200000
  const int e = in_sizes[1] / 2;    // 6400000
  const int half = n / 2;           // 100000
  const int* src = ei;
  const int* dst = ei + e;

  // workspace layout (~40.9 MB)
  char* ws = (char*)d_ws;
  int*      gcnt   = (int*)ws;      ws += (size_t)NBINS * 4;
  int*      gbase  = (int*)ws;      ws += ((size_t)NBINS + 1) * 4;
  int*      gcur   = (int*)ws;      ws += (size_t)NBINS * 4;
  unsigned* binned = (unsigned*)ws; ws += (size_t)e * 4;
  float*    dinv   = (float*)ws;    ws += (size_t)n * 4;
  __half*   hs1    = (__half*)ws;   ws += (size_t)n * 16 * 2;
  __half*   aggp   = (__half*)ws;   ws += (size_t)n * 16 * 2;
  float*    hs2    = (float*)ws;    ws += (size_t)n * 2 * 4;

  int gN = (n + BLK - 1) / BLK;
  int gC = (e + CHUNK - 1) / CHUNK;   // 196 binning blocks

  k_zero_i<<<(NBINS + BLK - 1) / BLK, BLK, 0, stream>>>(gcnt, NBINS);
  k_hist<<<gC, BLK, 0, stream>>>(src, dst, e, half, gcnt);
  k_scan<<<1, 1024, 0, stream>>>(gcnt, gbase, gcur, e);
  k_bin<<<gC, BLK, 0, stream>>>(src, dst, e, half, gcur, binned);
  k_ldeg<<<NB, BLK, 0, stream>>>(binned, gbase, dinv);
  k_transform1<<<gN, BLK, 0, stream>>>(x, W1, dinv, hs1, n);
  k_agg1A<<<NB, BLK, 0, stream>>>(binned, gbase, hs1, aggp);
  k_agg1B<<<NB, BLK, 0, stream>>>(binned, gbase, hs1, aggp, dinv, b1, W2, hs2);
  k_agg2<<<NB, BLK, 0, stream>>>(binned, gbase, hs2, dinv, b2, out);
}

// Round 8
// 480.085 us; speedup vs baseline: 1.9737x; 1.9205x over previous
//
#include <hip/hip_runtime.h>
#include <hip/hip_fp16.h>

#define BLK 256
#define ABLK 512             // agg1 block: 256 lane-pairs
#define NBK 782              // dst buckets of 256 nodes (782*256 >= 200000)
#define BW 256               // nodes per bucket (dl fits 8 bits)
#define CAP 9984             // edges counting-sorted per chunk (39.9 KB LDS)
#define CHUNK 32768          // edges per binning block

// ---------- bucket build ----------

__global__ void k_zero_i(int* __restrict__ p, int n) {
  int i = blockIdx.x * blockDim.x + threadIdx.x;
  if (i < n) p[i] = 0;
}

__global__ void k_hist(const int* __restrict__ dst, int e, int* __restrict__ gcnt) {
  __shared__ int h[NBK];
  for (int i = threadIdx.x; i < NBK; i += BLK) h[i] = 0;
  __syncthreads();
  int base = blockIdx.x * CHUNK;
  for (int k = 0; k < CHUNK; k += BLK) {
    int i = base + k + threadIdx.x;
    if (i < e) atomicAdd(&h[dst[i] >> 8], 1);
  }
  __syncthreads();
  for (int b = threadIdx.x; b < NBK; b += BLK) {
    int c = h[b];
    if (c) atomicAdd(&gcnt[b], c);
  }
}

// exclusive scan of gcnt[NBK] -> gbase[NBK+1]; init gcur. single block, 1024 thr.
__global__ void k_scan(const int* __restrict__ gcnt, int* __restrict__ gbase,
                       int* __restrict__ gcur, int e) {
  __shared__ int s[1024];
  int t = threadIdx.x;
  int v = (t < NBK) ? gcnt[t] : 0;
  s[t] = v;
  __syncthreads();
  for (int d = 1; d < 1024; d <<= 1) {
    int u = (t >= d) ? s[t - d] : 0;
    __syncthreads();
    s[t] += u;
    __syncthreads();
  }
  if (t < NBK) { int ex = s[t] - v; gbase[t] = ex; gcur[t] = ex; }
  if (t == 0) gbase[NBK] = e;
}

// bin edges by dst bucket: pack src(18b) | dl(8b)<<18
__global__ void k_bin(const int* __restrict__ src, const int* __restrict__ dst, int e,
                      int* __restrict__ gcur, unsigned* __restrict__ binned) {
  __shared__ int lcnt[NBK];
  __shared__ int lbase[NBK];
  int t = threadIdx.x;
  for (int i = t; i < NBK; i += BLK) lcnt[i] = 0;
  __syncthreads();
  int base = blockIdx.x * CHUNK;
  for (int k = 0; k < CHUNK; k += BLK) {
    int i = base + k + t;
    if (i < e) atomicAdd(&lcnt[dst[i] >> 8], 1);
  }
  __syncthreads();
  for (int b = t; b < NBK; b += BLK) {
    int c = lcnt[b];
    lbase[b] = c ? atomicAdd(&gcur[b], c) : 0;
    lcnt[b] = 0;
  }
  __syncthreads();
  for (int k = 0; k < CHUNK; k += BLK) {
    int i = base + k + t;
    if (i < e) {
      int d = dst[i];
      int b = d >> 8;
      int dl = d & 255;
      int pos = atomicAdd(&lcnt[b], 1);
      binned[lbase[b] + pos] = (unsigned)src[i] | ((unsigned)dl << 18);
    }
  }
}

// per-bucket degree -> dinv (deg = in-degree + 1 self-loop)
__global__ void k_ldeg(const unsigned* __restrict__ binned, const int* __restrict__ gbase,
                       float* __restrict__ dinv, int n) {
  __shared__ int cnt[BW];
  int t = threadIdx.x;
  cnt[t] = 0;
  __syncthreads();
  int b = blockIdx.x;
  int p0 = gbase[b], p1 = gbase[b + 1];
  for (int p = p0 + t; p < p1; p += BLK) atomicAdd(&cnt[binned[p] >> 18], 1);
  __syncthreads();
  int v = b * BW + t;
  if (v < n) dinv[v] = rsqrtf((float)cnt[t] + 1.0f);
}

// ---------- layer math ----------

// hs1 = fp16( (x @ W1) * dinv ), 32B rows
__global__ void k_transform1(const float* __restrict__ x, const float* __restrict__ W1,
                             const float* __restrict__ dinv, __half* __restrict__ hs1, int n) {
  __shared__ float w[160];
  int t = threadIdx.x;
  if (t < 160) w[t] = W1[t];
  __syncthreads();
  int i = blockIdx.x * blockDim.x + t;
  if (i >= n) return;
  float xi[10];
#pragma unroll
  for (int k = 0; k < 10; k++) xi[k] = x[i * 10 + k];
  float di = dinv[i];
  __half2 hv[8];
#pragma unroll
  for (int j = 0; j < 8; j++) {
    float acc0 = 0.f, acc1 = 0.f;
#pragma unroll
    for (int k = 0; k < 10; k++) {
      acc0 = fmaf(xi[k], w[k * 16 + 2 * j], acc0);
      acc1 = fmaf(xi[k], w[k * 16 + 2 * j + 1], acc1);
    }
    hv[j] = __floats2half2_rn(acc0 * di, acc1 * di);
  }
  float4* o = (float4*)(hs1 + (size_t)i * 16);
  o[0] = *(float4*)&hv[0];
  o[1] = *(float4*)&hv[4];
}

// layer-1 aggregation, ZERO float atomics: per bucket, counting-sort edges by dl in LDS,
// lane-pair (j = t>>1, c = t&1) owns dst j; each lane gathers its 16B half-row (same 64B
// line as partner -> merge candidate) and accumulates 8 fp32 in registers. Fused layer-2
// epilogue with 2x shfl_xor pair-combine.
__global__ void __launch_bounds__(ABLK) k_agg1s(const unsigned* __restrict__ binned,
                                                const int* __restrict__ gbase,
                                                const __half* __restrict__ hs1,
                                                const float* __restrict__ dinv,
                                                const float* __restrict__ b1,
                                                const float* __restrict__ W2,
                                                float* __restrict__ hs2, int n) {
  __shared__ int cnt[BW];
  __shared__ int stmp[BW];
  __shared__ int off[BW + 1];
  __shared__ int cur[BW];
  __shared__ int sorted[CAP];
  __shared__ float w2[32];
  __shared__ float sb1[16];
  int t = threadIdx.x;
  if (t < 32) w2[t] = W2[t];
  if (t >= 32 && t < 48) sb1[t - 32] = b1[t - 32];
  int bkt = blockIdx.x;
  int p0 = gbase[bkt], p1 = gbase[bkt + 1];
  const int j = t >> 1;
  const int c = t & 1;
  float acc[8];
#pragma unroll
  for (int q = 0; q < 8; q++) acc[q] = 0.f;

#define ACCR(R) { const __half2* h2_ = (const __half2*)&R; \
    float2 f0_ = __half22float2(h2_[0]); \
    float2 f1_ = __half22float2(h2_[1]); \
    float2 f2_ = __half22float2(h2_[2]); \
    float2 f3_ = __half22float2(h2_[3]); \
    acc[0] += f0_.x; acc[1] += f0_.y; acc[2] += f1_.x; acc[3] += f1_.y; \
    acc[4] += f2_.x; acc[5] += f2_.y; acc[6] += f3_.x; acc[7] += f3_.y; }

  int p = p0;
  while (p < p1) {
    int m = min(CAP, p1 - p);
    if (t < BW) cnt[t] = 0;
    __syncthreads();
    for (int i = t; i < m; i += ABLK) atomicAdd(&cnt[binned[p + i] >> 18], 1);
    __syncthreads();
    if (t < BW) stmp[t] = cnt[t];
    __syncthreads();
    for (int d = 1; d < BW; d <<= 1) {
      int u = 0;
      if (t < BW && t >= d) u = stmp[t - d];
      __syncthreads();
      if (t < BW) stmp[t] += u;
      __syncthreads();
    }
    if (t < BW) { int ex = stmp[t] - cnt[t]; off[t] = ex; cur[t] = ex; }
    if (t == 0) off[BW] = m;
    __syncthreads();
    for (int i = t; i < m; i += ABLK) {
      unsigned pk = binned[p + i];
      int pos = atomicAdd(&cur[pk >> 18], 1);
      sorted[pos] = (int)(pk & 0x3FFFF);
    }
    __syncthreads();
    // register gather over this dst's sorted segment
    int i0 = off[j], i1 = off[j + 1];
    int i = i0;
    for (; i + 3 < i1; i += 4) {
      int s0 = sorted[i + 0];
      int s1 = sorted[i + 1];
      int s2 = sorted[i + 2];
      int s3 = sorted[i + 3];
      float4 r0 = *(const float4*)(hs1 + (size_t)s0 * 16 + c * 8);
      float4 r1 = *(const float4*)(hs1 + (size_t)s1 * 16 + c * 8);
      float4 r2 = *(const float4*)(hs1 + (size_t)s2 * 16 + c * 8);
      float4 r3 = *(const float4*)(hs1 + (size_t)s3 * 16 + c * 8);
      ACCR(r0); ACCR(r1); ACCR(r2); ACCR(r3);
    }
    for (; i < i1; i++) {
      int s = sorted[i];
      float4 r = *(const float4*)(hs1 + (size_t)s * 16 + c * 8);
      ACCR(r);
    }
    __syncthreads();   // protect sorted/cnt before next chunk
    p += m;
  }
#undef ACCR

  // epilogue: + self term, dinv/b1/relu, @W2, pair-combine, write hs2
  int v = bkt * BW + j;
  if (v < n) {
    float di = dinv[v];
    float4 sf = *(const float4*)(hs1 + (size_t)v * 16 + c * 8);
    const __half2* sh = (const __half2*)&sf;
    float h0c = 0.f, h1c = 0.f;
#pragma unroll
    for (int q = 0; q < 4; q++) {
      float2 sv = __half22float2(sh[q]);
      int f0 = c * 8 + 2 * q;
      int f1 = f0 + 1;
      float a0 = fmaxf(fmaf(di, acc[2 * q + 0] + sv.x, sb1[f0]), 0.f);
      float a1 = fmaxf(fmaf(di, acc[2 * q + 1] + sv.y, sb1[f1]), 0.f);
      h0c = fmaf(a0, w2[f0 * 2 + 0], fmaf(a1, w2[f1 * 2 + 0], h0c));
      h1c = fmaf(a0, w2[f0 * 2 + 1], fmaf(a1, w2[f1 * 2 + 1], h1c));
    }
    float h0 = h0c + __shfl_xor(h0c, 1);
    float h1 = h1c + __shfl_xor(h1c, 1);
    if (c == 0) {
      hs2[(size_t)v * 2 + 0] = h0 * di;
      hs2[(size_t)v * 2 + 1] = h1 * di;
    }
  }
}

// layer-2 aggregate + output; hs2 = 1.6 MB L2-resident. LDS pad stride 3.
__global__ void k_agg2(const unsigned* __restrict__ binned, const int* __restrict__ gbase,
                       const float* __restrict__ hs2, const float* __restrict__ dinv,
                       const float* __restrict__ b2, float* __restrict__ out, int n) {
  __shared__ float agg[BW * 3];
  int t = threadIdx.x;
  for (int i = t; i < BW * 3; i += BLK) agg[i] = 0.f;
  __syncthreads();
  int bkt = blockIdx.x;
  int p0 = gbase[bkt], p1 = gbase[bkt + 1];
  int p = p0 + t;
#define ACC2(pk, M) { int dl_ = (pk) >> 18; \
    atomicAdd(&agg[dl_ * 3 + 0], M.x); atomicAdd(&agg[dl_ * 3 + 1], M.y); }
  for (; p + 3 * BLK < p1; p += 4 * BLK) {
    unsigned pk0 = binned[p];
    unsigned pk1 = binned[p + BLK];
    unsigned pk2 = binned[p + 2 * BLK];
    unsigned pk3 = binned[p + 3 * BLK];
    float2 m0 = *(const float2*)(hs2 + (size_t)(pk0 & 0x3FFFF) * 2);
    float2 m1 = *(const float2*)(hs2 + (size_t)(pk1 & 0x3FFFF) * 2);
    float2 m2 = *(const float2*)(hs2 + (size_t)(pk2 & 0x3FFFF) * 2);
    float2 m3 = *(const float2*)(hs2 + (size_t)(pk3 & 0x3FFFF) * 2);
    ACC2(pk0, m0); ACC2(pk1, m1); ACC2(pk2, m2); ACC2(pk3, m3);
  }
  for (; p < p1; p += BLK) {
    unsigned pk = binned[p];
    float2 m = *(const float2*)(hs2 + (size_t)(pk & 0x3FFFF) * 2);
    ACC2(pk, m);
  }
#undef ACC2
  __syncthreads();
  int v = bkt * BW + t;
  if (v < n) {
    float di = dinv[v];
    out[(size_t)v * 2 + 0] = fmaf(di, agg[t * 3 + 0] + hs2[(size_t)v * 2 + 0], b2[0]);
    out[(size_t)v * 2 + 1] = fmaf(di, agg[t * 3 + 1] + hs2[(size_t)v * 2 + 1], b2[1]);
  }
}

extern "C" void kernel_launch(void* const* d_in, const int* in_sizes, int n_in,
                              void* d_out, int out_size, void* d_ws, size_t ws_size,
                              hipStream_t stream) {
  const float* x  = (const float*)d_in[0];
  const int*   ei = (const int*)d_in[1];
  const float* W1 = (const float*)d_in[2];
  const float* b1 = (const float*)d_in[3];
  const float* W2 = (const float*)d_in[4];
  const float* b2 = (const float*)d_in[5];
  float* out = (float*)d_out;

  const int n = in_sizes[0] / 10;   // 200000
  const int e = in_sizes[1] / 2;    // 6400000
  const int* src = ei;
  const int* dst = ei + e;

  // workspace layout (~34.5 MB)
  char* ws = (char*)d_ws;
  int*      gcnt   = (int*)ws;      ws += (size_t)NBK * 4;
  int*      gbase  = (int*)ws;      ws += ((size_t)NBK + 1) * 4;
  int*      gcur   = (int*)ws;      ws += (size_t)NBK * 4;
  unsigned* binned = (unsigned*)ws; ws += (size_t)e * 4;
  float*    dinv   = (float*)ws;    ws += (size_t)n * 4;
  __half*   hs1    = (__half*)ws;   ws += (size_t)n * 16 * 2;
  float*    hs2    = (float*)ws;    ws += (size_t)n * 2 * 4;

  int gN = (n + BLK - 1) / BLK;
  int gC = (e + CHUNK - 1) / CHUNK;   // 196 binning blocks

  k_zero_i<<<(NBK + BLK - 1) / BLK, BLK, 0, stream>>>(gcnt, NBK);
  k_hist<<<gC, BLK, 0, stream>>>(dst, e, gcnt);
  k_scan<<<1, 1024, 0, stream>>>(gcnt, gbase, gcur, e);
  k_bin<<<gC, BLK, 0, stream>>>(src, dst, e, gcur, binned);
  k_ldeg<<<NBK, BLK, 0, stream>>>(binned, gbase, dinv, n);
  k_transform1<<<gN, BLK, 0, stream>>>(x, W1, dinv, hs1, n);
  k_agg1s<<<NBK, ABLK, 0, stream>>>(binned, gbase, hs1, dinv, b1, W2, hs2, n);
  k_agg2<<<NBK, BLK, 0, stream>>>(binned, gbase, hs2, dinv, b2, out, n);
}

// Round 9
// 438.402 us; speedup vs baseline: 2.1613x; 1.0951x over previous
//
#include <hip/hip_runtime.h>
#include <hip/hip_fp16.h>

#define BLK 256
#define ABLK 512             // agg1 block: 256 lane-pairs
#define NBK 782              // dst buckets of 256 nodes (782*256 >= 200000)
#define BW 256               // nodes per bucket (dl fits 8 bits)
#define CAP 9984             // edges counting-sorted per chunk (39.9 KB LDS)
#define CHUNK 8192           // edges per binning block -> 782 blocks (~3/CU)

// ---------- bucket build ----------

__global__ void k_zero_i(int* __restrict__ p, int n) {
  int i = blockIdx.x * blockDim.x + threadIdx.x;
  if (i < n) p[i] = 0;
}

__global__ void k_hist(const int* __restrict__ dst, int e, int* __restrict__ gcnt) {
  __shared__ int h[NBK];
  for (int i = threadIdx.x; i < NBK; i += BLK) h[i] = 0;
  __syncthreads();
  int base = blockIdx.x * CHUNK;
  for (int k = 0; k < CHUNK; k += BLK) {
    int i = base + k + threadIdx.x;
    if (i < e) atomicAdd(&h[dst[i] >> 8], 1);
  }
  __syncthreads();
  for (int b = threadIdx.x; b < NBK; b += BLK) {
    int c = h[b];
    if (c) atomicAdd(&gcnt[b], c);
  }
}

// exclusive scan of gcnt[NBK] -> gbase[NBK+1]; init gcur. single block, 1024 thr.
__global__ void k_scan(const int* __restrict__ gcnt, int* __restrict__ gbase,
                       int* __restrict__ gcur, int e) {
  __shared__ int s[1024];
  int t = threadIdx.x;
  int v = (t < NBK) ? gcnt[t] : 0;
  s[t] = v;
  __syncthreads();
  for (int d = 1; d < 1024; d <<= 1) {
    int u = (t >= d) ? s[t - d] : 0;
    __syncthreads();
    s[t] += u;
    __syncthreads();
  }
  if (t < NBK) { int ex = s[t] - v; gbase[t] = ex; gcur[t] = ex; }
  if (t == 0) gbase[NBK] = e;
}

// bin edges by dst bucket: pack src(18b) | dl(8b)<<18
__global__ void k_bin(const int* __restrict__ src, const int* __restrict__ dst, int e,
                      int* __restrict__ gcur, unsigned* __restrict__ binned) {
  __shared__ int lcnt[NBK];
  __shared__ int lbase[NBK];
  int t = threadIdx.x;
  for (int i = t; i < NBK; i += BLK) lcnt[i] = 0;
  __syncthreads();
  int base = blockIdx.x * CHUNK;
  for (int k = 0; k < CHUNK; k += BLK) {
    int i = base + k + t;
    if (i < e) atomicAdd(&lcnt[dst[i] >> 8], 1);
  }
  __syncthreads();
  for (int b = t; b < NBK; b += BLK) {
    int c = lcnt[b];
    lbase[b] = c ? atomicAdd(&gcur[b], c) : 0;
    lcnt[b] = 0;
  }
  __syncthreads();
  for (int k = 0; k < CHUNK; k += BLK) {
    int i = base + k + t;
    if (i < e) {
      int d = dst[i];
      int b = d >> 8;
      int dl = d & 255;
      int pos = atomicAdd(&lcnt[b], 1);
      binned[lbase[b] + pos] = (unsigned)src[i] | ((unsigned)dl << 18);
    }
  }
}

// per-bucket degree -> dinv (deg = in-degree + 1 self-loop)
__global__ void k_ldeg(const unsigned* __restrict__ binned, const int* __restrict__ gbase,
                       float* __restrict__ dinv, int n) {
  __shared__ int cnt[BW];
  int t = threadIdx.x;
  cnt[t] = 0;
  __syncthreads();
  int b = blockIdx.x;
  int p0 = gbase[b], p1 = gbase[b + 1];
  for (int p = p0 + t; p < p1; p += BLK) atomicAdd(&cnt[binned[p] >> 18], 1);
  __syncthreads();
  int v = b * BW + t;
  if (v < n) dinv[v] = rsqrtf((float)cnt[t] + 1.0f);
}

// ---------- layer math ----------

// hs1 = fp16( (x @ W1) * dinv ), 32B rows
__global__ void k_transform1(const float* __restrict__ x, const float* __restrict__ W1,
                             const float* __restrict__ dinv, __half* __restrict__ hs1, int n) {
  __shared__ float w[160];
  int t = threadIdx.x;
  if (t < 160) w[t] = W1[t];
  __syncthreads();
  int i = blockIdx.x * blockDim.x + t;
  if (i >= n) return;
  float xi[10];
#pragma unroll
  for (int k = 0; k < 10; k++) xi[k] = x[i * 10 + k];
  float di = dinv[i];
  __half2 hv[8];
#pragma unroll
  for (int j = 0; j < 8; j++) {
    float acc0 = 0.f, acc1 = 0.f;
#pragma unroll
    for (int k = 0; k < 10; k++) {
      acc0 = fmaf(xi[k], w[k * 16 + 2 * j], acc0);
      acc1 = fmaf(xi[k], w[k * 16 + 2 * j + 1], acc1);
    }
    hv[j] = __floats2half2_rn(acc0 * di, acc1 * di);
  }
  float4* o = (float4*)(hs1 + (size_t)i * 16);
  o[0] = *(float4*)&hv[0];
  o[1] = *(float4*)&hv[4];
}

// layer-1 aggregation, ZERO float atomics: per bucket, counting-sort edges by dl in LDS,
// lane-pair (j = t>>1, c = t&1) owns dst j; each lane gathers its 16B half-row (same 64B
// line as partner -> merge candidate) and accumulates 8 fp32 in registers. Fused layer-2
// epilogue with shfl_xor pair-combine.
__global__ void __launch_bounds__(ABLK) k_agg1s(const unsigned* __restrict__ binned,
                                                const int* __restrict__ gbase,
                                                const __half* __restrict__ hs1,
                                                const float* __restrict__ dinv,
                                                const float* __restrict__ b1,
                                                const float* __restrict__ W2,
                                                float* __restrict__ hs2, int n) {
  __shared__ int cnt[BW];
  __shared__ int stmp[BW];
  __shared__ int off[BW + 1];
  __shared__ int cur[BW];
  __shared__ int sorted[CAP];
  __shared__ float w2[32];
  __shared__ float sb1[16];
  int t = threadIdx.x;
  if (t < 32) w2[t] = W2[t];
  if (t >= 32 && t < 48) sb1[t - 32] = b1[t - 32];
  int bkt = blockIdx.x;
  int p0 = gbase[bkt], p1 = gbase[bkt + 1];
  const int j = t >> 1;
  const int c = t & 1;
  float acc[8];
#pragma unroll
  for (int q = 0; q < 8; q++) acc[q] = 0.f;

#define ACCR(R) { const __half2* h2_ = (const __half2*)&R; \
    float2 f0_ = __half22float2(h2_[0]); \
    float2 f1_ = __half22float2(h2_[1]); \
    float2 f2_ = __half22float2(h2_[2]); \
    float2 f3_ = __half22float2(h2_[3]); \
    acc[0] += f0_.x; acc[1] += f0_.y; acc[2] += f1_.x; acc[3] += f1_.y; \
    acc[4] += f2_.x; acc[5] += f2_.y; acc[6] += f3_.x; acc[7] += f3_.y; }

  int p = p0;
  while (p < p1) {
    int m = min(CAP, p1 - p);
    if (t < BW) cnt[t] = 0;
    __syncthreads();
    for (int i = t; i < m; i += ABLK) atomicAdd(&cnt[binned[p + i] >> 18], 1);
    __syncthreads();
    if (t < BW) stmp[t] = cnt[t];
    __syncthreads();
    for (int d = 1; d < BW; d <<= 1) {
      int u = 0;
      if (t < BW && t >= d) u = stmp[t - d];
      __syncthreads();
      if (t < BW) stmp[t] += u;
      __syncthreads();
    }
    if (t < BW) { int ex = stmp[t] - cnt[t]; off[t] = ex; cur[t] = ex; }
    if (t == 0) off[BW] = m;
    __syncthreads();
    for (int i = t; i < m; i += ABLK) {
      unsigned pk = binned[p + i];
      int pos = atomicAdd(&cur[pk >> 18], 1);
      sorted[pos] = (int)(pk & 0x3FFFF);
    }
    __syncthreads();
    // register gather over this dst's sorted segment
    int i0 = off[j], i1 = off[j + 1];
    int i = i0;
    for (; i + 3 < i1; i += 4) {
      int s0 = sorted[i + 0];
      int s1 = sorted[i + 1];
      int s2 = sorted[i + 2];
      int s3 = sorted[i + 3];
      float4 r0 = *(const float4*)(hs1 + (size_t)s0 * 16 + c * 8);
      float4 r1 = *(const float4*)(hs1 + (size_t)s1 * 16 + c * 8);
      float4 r2 = *(const float4*)(hs1 + (size_t)s2 * 16 + c * 8);
      float4 r3 = *(const float4*)(hs1 + (size_t)s3 * 16 + c * 8);
      ACCR(r0); ACCR(r1); ACCR(r2); ACCR(r3);
    }
    for (; i < i1; i++) {
      int s = sorted[i];
      float4 r = *(const float4*)(hs1 + (size_t)s * 16 + c * 8);
      ACCR(r);
    }
    __syncthreads();   // protect sorted/cnt before next chunk
    p += m;
  }
#undef ACCR

  // epilogue: + self term, dinv/b1/relu, @W2, pair-combine, write hs2
  int v = bkt * BW + j;
  if (v < n) {
    float di = dinv[v];
    float4 sf = *(const float4*)(hs1 + (size_t)v * 16 + c * 8);
    const __half2* sh = (const __half2*)&sf;
    float h0c = 0.f, h1c = 0.f;
#pragma unroll
    for (int q = 0; q < 4; q++) {
      float2 sv = __half22float2(sh[q]);
      int f0 = c * 8 + 2 * q;
      int f1 = f0 + 1;
      float a0 = fmaxf(fmaf(di, acc[2 * q + 0] + sv.x, sb1[f0]), 0.f);
      float a1 = fmaxf(fmaf(di, acc[2 * q + 1] + sv.y, sb1[f1]), 0.f);
      h0c = fmaf(a0, w2[f0 * 2 + 0], fmaf(a1, w2[f1 * 2 + 0], h0c));
      h1c = fmaf(a0, w2[f0 * 2 + 1], fmaf(a1, w2[f1 * 2 + 1], h1c));
    }
    float h0 = h0c + __shfl_xor(h0c, 1);
    float h1 = h1c + __shfl_xor(h1c, 1);
    if (c == 0) {
      hs2[(size_t)v * 2 + 0] = h0 * di;
      hs2[(size_t)v * 2 + 1] = h1 * di;
    }
  }
}

// layer-2 aggregate + output; hs2 = 1.6 MB L2-resident. LDS pad stride 3.
__global__ void k_agg2(const unsigned* __restrict__ binned, const int* __restrict__ gbase,
                       const float* __restrict__ hs2, const float* __restrict__ dinv,
                       const float* __restrict__ b2, float* __restrict__ out, int n) {
  __shared__ float agg[BW * 3];
  int t = threadIdx.x;
  for (int i = t; i < BW * 3; i += BLK) agg[i] = 0.f;
  __syncthreads();
  int bkt = blockIdx.x;
  int p0 = gbase[bkt], p1 = gbase[bkt + 1];
  int p = p0 + t;
#define ACC2(pk, M) { int dl_ = (pk) >> 18; \
    atomicAdd(&agg[dl_ * 3 + 0], M.x); atomicAdd(&agg[dl_ * 3 + 1], M.y); }
  for (; p + 3 * BLK < p1; p += 4 * BLK) {
    unsigned pk0 = binned[p];
    unsigned pk1 = binned[p + BLK];
    unsigned pk2 = binned[p + 2 * BLK];
    unsigned pk3 = binned[p + 3 * BLK];
    float2 m0 = *(const float2*)(hs2 + (size_t)(pk0 & 0x3FFFF) * 2);
    float2 m1 = *(const float2*)(hs2 + (size_t)(pk1 & 0x3FFFF) * 2);
    float2 m2 = *(const float2*)(hs2 + (size_t)(pk2 & 0x3FFFF) * 2);
    float2 m3 = *(const float2*)(hs2 + (size_t)(pk3 & 0x3FFFF) * 2);
    ACC2(pk0, m0); ACC2(pk1, m1); ACC2(pk2, m2); ACC2(pk3, m3);
  }
  for (; p < p1; p += BLK) {
    unsigned pk = binned[p];
    float2 m = *(const float2*)(hs2 + (size_t)(pk & 0x3FFFF) * 2);
    ACC2(pk, m);
  }
#undef ACC2
  __syncthreads();
  int v = bkt * BW + t;
  if (v < n) {
    float di = dinv[v];
    out[(size_t)v * 2 + 0] = fmaf(di, agg[t * 3 + 0] + hs2[(size_t)v * 2 + 0], b2[0]);
    out[(size_t)v * 2 + 1] = fmaf(di, agg[t * 3 + 1] + hs2[(size_t)v * 2 + 1], b2[1]);
  }
}

extern "C" void kernel_launch(void* const* d_in, const int* in_sizes, int n_in,
                              void* d_out, int out_size, void* d_ws, size_t ws_size,
                              hipStream_t stream) {
  const float* x  = (const float*)d_in[0];
  const int*   ei = (const int*)d_in[1];
  const float* W1 = (const float*)d_in[2];
  const float* b1 = (const float*)d_in[3];
  const float* W2 = (const float*)d_in[4];
  const float* b2 = (const float*)d_in[5];
  float* out = (float*)d_out;

  const int n = in_sizes[0] / 10;   // 200000
  const int e = in_sizes[1] / 2;    // 6400000
  const int* src = ei;
  const int* dst = ei + e;

  // workspace layout (~34.5 MB)
  char* ws = (char*)d_ws;
  int*      gcnt   = (int*)ws;      ws += (size_t)NBK * 4;
  int*      gbase  = (int*)ws;      ws += ((size_t)NBK + 1) * 4;
  int*      gcur   = (int*)ws;      ws += (size_t)NBK * 4;
  unsigned* binned = (unsigned*)ws; ws += (size_t)e * 4;
  float*    dinv   = (float*)ws;    ws += (size_t)n * 4;
  __half*   hs1    = (__half*)ws;   ws += (size_t)n * 16 * 2;
  float*    hs2    = (float*)ws;    ws += (size_t)n * 2 * 4;

  int gN = (n + BLK - 1) / BLK;
  int gC = (e + CHUNK - 1) / CHUNK;   // 782 binning blocks (~3/CU)

  k_zero_i<<<(NBK + BLK - 1) / BLK, BLK, 0, stream>>>(gcnt, NBK);
  k_hist<<<gC, BLK, 0, stream>>>(dst, e, gcnt);
  k_scan<<<1, 1024, 0, stream>>>(gcnt, gbase, gcur, e);
  k_bin<<<gC, BLK, 0, stream>>>(src, dst, e, gcur, binned);
  k_ldeg<<<NBK, BLK, 0, stream>>>(binned, gbase, dinv, n);
  k_transform1<<<gN, BLK, 0, stream>>>(x, W1, dinv, hs1, n);
  k_agg1s<<<NBK, ABLK, 0, stream>>>(binned, gbase, hs1, dinv, b1, W2, hs2, n);
  k_agg2<<<NBK, BLK, 0, stream>>>(binned, gbase, hs2, dinv, b2, out, n);
}

// Round 10
// 417.141 us; speedup vs baseline: 2.2715x; 1.0510x over previous
//
#include <hip/hip_runtime.h>
#include <hip/hip_fp16.h>

#define BLK 256
#define ABLK 512             // agg1 block: 256 lane-pairs
#define NBK 782              // dst buckets of 256 nodes (782*256 >= 200000)
#define BW 256               // nodes per bucket (dl fits 8 bits)
#define CAP 9984             // edges counting-sorted per chunk in agg1 (39.9 KB LDS)
#define CHUNK 8192           // edges per binning block -> 782 blocks

// ---------- bucket build ----------

__global__ void k_zero_i(int* __restrict__ p, int n) {
  int i = blockIdx.x * blockDim.x + threadIdx.x;
  if (i < n) p[i] = 0;
}

__global__ void k_hist(const int* __restrict__ dst, int e, int* __restrict__ gcnt) {
  __shared__ int h[NBK];
  for (int i = threadIdx.x; i < NBK; i += BLK) h[i] = 0;
  __syncthreads();
  int base = blockIdx.x * CHUNK;
  for (int k = 0; k < CHUNK; k += BLK) {
    int i = base + k + threadIdx.x;
    if (i < e) atomicAdd(&h[dst[i] >> 8], 1);
  }
  __syncthreads();
  for (int b = threadIdx.x; b < NBK; b += BLK) {
    int c = h[b];
    if (c) atomicAdd(&gcnt[b], c);
  }
}

// exclusive scan of gcnt[NBK] -> gbase[NBK+1]; init gcur. single block, 1024 thr.
__global__ void k_scan(const int* __restrict__ gcnt, int* __restrict__ gbase,
                       int* __restrict__ gcur, int e) {
  __shared__ int s[1024];
  int t = threadIdx.x;
  int v = (t < NBK) ? gcnt[t] : 0;
  s[t] = v;
  __syncthreads();
  for (int d = 1; d < 1024; d <<= 1) {
    int u = (t >= d) ? s[t - d] : 0;
    __syncthreads();
    s[t] += u;
    __syncthreads();
  }
  if (t < NBK) { int ex = s[t] - v; gbase[t] = ex; gcur[t] = ex; }
  if (t == 0) gbase[NBK] = e;
}

// bin edges by dst bucket with LDS counting-sort so global stores are lane-coalesced.
// pack src(18b) | dl(8b)<<18
__global__ void __launch_bounds__(BLK) k_bin(const int* __restrict__ src,
                                             const int* __restrict__ dst, int e,
                                             int* __restrict__ gcur,
                                             unsigned* __restrict__ binned) {
  __shared__ int lcnt[NBK];
  __shared__ int loff[NBK + 1];
  __shared__ int lcur[NBK];
  __shared__ int lbase[NBK];
  __shared__ int part[BLK];
  __shared__ unsigned sorted[CHUNK];   // 32 KB
  int t = threadIdx.x;
  int base = blockIdx.x * CHUNK;
  int m = min(CHUNK, e - base);

  for (int i = t; i < NBK; i += BLK) lcnt[i] = 0;
  __syncthreads();
  // 1. histogram
  for (int k = t; k < m; k += BLK) atomicAdd(&lcnt[dst[base + k] >> 8], 1);
  __syncthreads();
  // 2. exclusive scan over 782 bins (4 bins/thread + Hillis-Steele over 256 partials)
  int b0 = 4 * t;
  int s0 = (b0 + 0 < NBK) ? lcnt[b0 + 0] : 0;
  int s1 = (b0 + 1 < NBK) ? lcnt[b0 + 1] : 0;
  int s2 = (b0 + 2 < NBK) ? lcnt[b0 + 2] : 0;
  int s3 = (b0 + 3 < NBK) ? lcnt[b0 + 3] : 0;
  int tsum = s0 + s1 + s2 + s3;
  part[t] = tsum;
  __syncthreads();
  for (int d = 1; d < BLK; d <<= 1) {
    int u = (t >= d) ? part[t - d] : 0;
    __syncthreads();
    part[t] += u;
    __syncthreads();
  }
  int ex = part[t] - tsum;
  if (b0 + 0 < NBK) loff[b0 + 0] = ex;
  if (b0 + 1 < NBK) loff[b0 + 1] = ex + s0;
  if (b0 + 2 < NBK) loff[b0 + 2] = ex + s0 + s1;
  if (b0 + 3 < NBK) loff[b0 + 3] = ex + s0 + s1 + s2;
  if (t == 0) loff[NBK] = m;
  __syncthreads();
  // 3. reserve global windows, init cursors
  for (int b = t; b < NBK; b += BLK) {
    int c = lcnt[b];
    lbase[b] = c ? atomicAdd(&gcur[b], c) : 0;
    lcur[b] = loff[b];
  }
  __syncthreads();
  // 4. scatter into LDS sorted order
  for (int k = t; k < m; k += BLK) {
    int d = dst[base + k];
    int b = d >> 8;
    int dl = d & 255;
    int pos = atomicAdd(&lcur[b], 1);
    sorted[pos] = (unsigned)src[base + k] | ((unsigned)dl << 18);
  }
  __syncthreads();
  // 5. coalesced write-out: consecutive i -> consecutive addresses within runs
  for (int i = t; i < m; i += BLK) {
    int lo = 0, hi = NBK;            // find b: loff[b] <= i < loff[b+1]
    while (hi - lo > 1) {
      int mid = (lo + hi) >> 1;
      if (loff[mid] <= i) lo = mid; else hi = mid;
    }
    binned[lbase[lo] + (i - loff[lo])] = sorted[i];
  }
}

// per-bucket degree -> dinv (deg = in-degree + 1 self-loop)
__global__ void k_ldeg(const unsigned* __restrict__ binned, const int* __restrict__ gbase,
                       float* __restrict__ dinv, int n) {
  __shared__ int cnt[BW];
  int t = threadIdx.x;
  cnt[t] = 0;
  __syncthreads();
  int b = blockIdx.x;
  int p0 = gbase[b], p1 = gbase[b + 1];
  for (int p = p0 + t; p < p1; p += BLK) atomicAdd(&cnt[binned[p] >> 18], 1);
  __syncthreads();
  int v = b * BW + t;
  if (v < n) dinv[v] = rsqrtf((float)cnt[t] + 1.0f);
}

// ---------- layer math ----------

// hs1 = fp16( (x @ W1) * dinv ), 32B rows
__global__ void k_transform1(const float* __restrict__ x, const float* __restrict__ W1,
                             const float* __restrict__ dinv, __half* __restrict__ hs1, int n) {
  __shared__ float w[160];
  int t = threadIdx.x;
  if (t < 160) w[t] = W1[t];
  __syncthreads();
  int i = blockIdx.x * blockDim.x + t;
  if (i >= n) return;
  float xi[10];
#pragma unroll
  for (int k = 0; k < 10; k++) xi[k] = x[i * 10 + k];
  float di = dinv[i];
  __half2 hv[8];
#pragma unroll
  for (int j = 0; j < 8; j++) {
    float acc0 = 0.f, acc1 = 0.f;
#pragma unroll
    for (int k = 0; k < 10; k++) {
      acc0 = fmaf(xi[k], w[k * 16 + 2 * j], acc0);
      acc1 = fmaf(xi[k], w[k * 16 + 2 * j + 1], acc1);
    }
    hv[j] = __floats2half2_rn(acc0 * di, acc1 * di);
  }
  float4* o = (float4*)(hs1 + (size_t)i * 16);
  o[0] = *(float4*)&hv[0];
  o[1] = *(float4*)&hv[4];
}

// layer-1 aggregation, zero float atomics: counting-sort by dl in LDS, lane-pair register
// accumulate, fused layer-2 epilogue.
__global__ void __launch_bounds__(ABLK) k_agg1s(const unsigned* __restrict__ binned,
                                                const int* __restrict__ gbase,
                                                const __half* __restrict__ hs1,
                                                const float* __restrict__ dinv,
                                                const float* __restrict__ b1,
                                                const float* __restrict__ W2,
                                                float* __restrict__ hs2, int n) {
  __shared__ int cnt[BW];
  __shared__ int stmp[BW];
  __shared__ int off[BW + 1];
  __shared__ int cur[BW];
  __shared__ int sorted[CAP];
  __shared__ float w2[32];
  __shared__ float sb1[16];
  int t = threadIdx.x;
  if (t < 32) w2[t] = W2[t];
  if (t >= 32 && t < 48) sb1[t - 32] = b1[t - 32];
  int bkt = blockIdx.x;
  int p0 = gbase[bkt], p1 = gbase[bkt + 1];
  const int j = t >> 1;
  const int c = t & 1;
  float acc[8];
#pragma unroll
  for (int q = 0; q < 8; q++) acc[q] = 0.f;

#define ACCR(R) { const __half2* h2_ = (const __half2*)&R; \
    float2 f0_ = __half22float2(h2_[0]); \
    float2 f1_ = __half22float2(h2_[1]); \
    float2 f2_ = __half22float2(h2_[2]); \
    float2 f3_ = __half22float2(h2_[3]); \
    acc[0] += f0_.x; acc[1] += f0_.y; acc[2] += f1_.x; acc[3] += f1_.y; \
    acc[4] += f2_.x; acc[5] += f2_.y; acc[6] += f3_.x; acc[7] += f3_.y; }

  int p = p0;
  while (p < p1) {
    int m = min(CAP, p1 - p);
    if (t < BW) cnt[t] = 0;
    __syncthreads();
    for (int i = t; i < m; i += ABLK) atomicAdd(&cnt[binned[p + i] >> 18], 1);
    __syncthreads();
    if (t < BW) stmp[t] = cnt[t];
    __syncthreads();
    for (int d = 1; d < BW; d <<= 1) {
      int u = 0;
      if (t < BW && t >= d) u = stmp[t - d];
      __syncthreads();
      if (t < BW) stmp[t] += u;
      __syncthreads();
    }
    if (t < BW) { int ex = stmp[t] - cnt[t]; off[t] = ex; cur[t] = ex; }
    if (t == 0) off[BW] = m;
    __syncthreads();
    for (int i = t; i < m; i += ABLK) {
      unsigned pk = binned[p + i];
      int pos = atomicAdd(&cur[pk >> 18], 1);
      sorted[pos] = (int)(pk & 0x3FFFF);
    }
    __syncthreads();
    int i0 = off[j], i1 = off[j + 1];
    int i = i0;
    for (; i + 3 < i1; i += 4) {
      int s0 = sorted[i + 0];
      int s1 = sorted[i + 1];
      int s2 = sorted[i + 2];
      int s3 = sorted[i + 3];
      float4 r0 = *(const float4*)(hs1 + (size_t)s0 * 16 + c * 8);
      float4 r1 = *(const float4*)(hs1 + (size_t)s1 * 16 + c * 8);
      float4 r2 = *(const float4*)(hs1 + (size_t)s2 * 16 + c * 8);
      float4 r3 = *(const float4*)(hs1 + (size_t)s3 * 16 + c * 8);
      ACCR(r0); ACCR(r1); ACCR(r2); ACCR(r3);
    }
    for (; i < i1; i++) {
      int s = sorted[i];
      float4 r = *(const float4*)(hs1 + (size_t)s * 16 + c * 8);
      ACCR(r);
    }
    __syncthreads();
    p += m;
  }
#undef ACCR

  int v = bkt * BW + j;
  if (v < n) {
    float di = dinv[v];
    float4 sf = *(const float4*)(hs1 + (size_t)v * 16 + c * 8);
    const __half2* sh = (const __half2*)&sf;
    float h0c = 0.f, h1c = 0.f;
#pragma unroll
    for (int q = 0; q < 4; q++) {
      float2 sv = __half22float2(sh[q]);
      int f0 = c * 8 + 2 * q;
      int f1 = f0 + 1;
      float a0 = fmaxf(fmaf(di, acc[2 * q + 0] + sv.x, sb1[f0]), 0.f);
      float a1 = fmaxf(fmaf(di, acc[2 * q + 1] + sv.y, sb1[f1]), 0.f);
      h0c = fmaf(a0, w2[f0 * 2 + 0], fmaf(a1, w2[f1 * 2 + 0], h0c));
      h1c = fmaf(a0, w2[f0 * 2 + 1], fmaf(a1, w2[f1 * 2 + 1], h1c));
    }
    float h0 = h0c + __shfl_xor(h0c, 1);
    float h1 = h1c + __shfl_xor(h1c, 1);
    if (c == 0) {
      hs2[(size_t)v * 2 + 0] = h0 * di;
      hs2[(size_t)v * 2 + 1] = h1 * di;
    }
  }
}

// layer-2 aggregate + output; hs2 = 1.6 MB L2-resident. LDS pad stride 3.
__global__ void k_agg2(const unsigned* __restrict__ binned, const int* __restrict__ gbase,
                       const float* __restrict__ hs2, const float* __restrict__ dinv,
                       const float* __restrict__ b2, float* __restrict__ out, int n) {
  __shared__ float agg[BW * 3];
  int t = threadIdx.x;
  for (int i = t; i < BW * 3; i += BLK) agg[i] = 0.f;
  __syncthreads();
  int bkt = blockIdx.x;
  int p0 = gbase[bkt], p1 = gbase[bkt + 1];
  int p = p0 + t;
#define ACC2(pk, M) { int dl_ = (pk) >> 18; \
    atomicAdd(&agg[dl_ * 3 + 0], M.x); atomicAdd(&agg[dl_ * 3 + 1], M.y); }
  for (; p + 3 * BLK < p1; p += 4 * BLK) {
    unsigned pk0 = binned[p];
    unsigned pk1 = binned[p + BLK];
    unsigned pk2 = binned[p + 2 * BLK];
    unsigned pk3 = binned[p + 3 * BLK];
    float2 m0 = *(const float2*)(hs2 + (size_t)(pk0 & 0x3FFFF) * 2);
    float2 m1 = *(const float2*)(hs2 + (size_t)(pk1 & 0x3FFFF) * 2);
    float2 m2 = *(const float2*)(hs2 + (size_t)(pk2 & 0x3FFFF) * 2);
    float2 m3 = *(const float2*)(hs2 + (size_t)(pk3 & 0x3FFFF) * 2);
    ACC2(pk0, m0); ACC2(pk1, m1); ACC2(pk2, m2); ACC2(pk3, m3);
  }
  for (; p < p1; p += BLK) {
    unsigned pk = binned[p];
    float2 m = *(const float2*)(hs2 + (size_t)(pk & 0x3FFFF) * 2);
    ACC2(pk, m);
  }
#undef ACC2
  __syncthreads();
  int v = bkt * BW + t;
  if (v < n) {
    float di = dinv[v];
    out[(size_t)v * 2 + 0] = fmaf(di, agg[t * 3 + 0] + hs2[(size_t)v * 2 + 0], b2[0]);
    out[(size_t)v * 2 + 1] = fmaf(di, agg[t * 3 + 1] + hs2[(size_t)v * 2 + 1], b2[1]);
  }
}

extern "C" void kernel_launch(void* const* d_in, const int* in_sizes, int n_in,
                              void* d_out, int out_size, void* d_ws, size_t ws_size,
                              hipStream_t stream) {
  const float* x  = (const float*)d_in[0];
  const int*   ei = (const int*)d_in[1];
  const float* W1 = (const float*)d_in[2];
  const float* b1 = (const float*)d_in[3];
  const float* W2 = (const float*)d_in[4];
  const float* b2 = (const float*)d_in[5];
  float* out = (float*)d_out;

  const int n = in_sizes[0] / 10;   // 200000
  const int e = in_sizes[1] / 2;    // 6400000
  const int* src = ei;
  const int* dst = ei + e;

  // workspace layout (~34.5 MB)
  char* ws = (char*)d_ws;
  int*      gcnt   = (int*)ws;      ws += (size_t)NBK * 4;
  int*      gbase  = (int*)ws;      ws += ((size_t)NBK + 1) * 4;
  int*      gcur   = (int*)ws;      ws += (size_t)NBK * 4;
  unsigned* binned = (unsigned*)ws; ws += (size_t)e * 4;
  float*    dinv   = (float*)ws;    ws += (size_t)n * 4;
  __half*   hs1    = (__half*)ws;   ws += (size_t)n * 16 * 2;
  float*    hs2    = (float*)ws;    ws += (size_t)n * 2 * 4;

  int gN = (n + BLK - 1) / BLK;
  int gC = (e + CHUNK - 1) / CHUNK;   // 782 binning blocks

  k_zero_i<<<(NBK + BLK - 1) / BLK, BLK, 0, stream>>>(gcnt, NBK);
  k_hist<<<gC, BLK, 0, stream>>>(dst, e, gcnt);
  k_scan<<<1, 1024, 0, stream>>>(gcnt, gbase, gcur, e);
  k_bin<<<gC, BLK, 0, stream>>>(src, dst, e, gcur, binned);
  k_ldeg<<<NBK, BLK, 0, stream>>>(binned, gbase, dinv, n);
  k_transform1<<<gN, BLK, 0, stream>>>(x, W1, dinv, hs1, n);
  k_agg1s<<<NBK, ABLK, 0, stream>>>(binned, gbase, hs1, dinv, b1, W2, hs2, n);
  k_agg2<<<NBK, BLK, 0, stream>>>(binned, gbase, hs2, dinv, b2, out, n);
}

// Round 11
// 393.003 us; speedup vs baseline: 2.4110x; 1.0614x over previous
//
#include <hip/hip_runtime.h>
#include <hip/hip_fp16.h>

#define BLK 256
#define ABLK 512             // agg1 block: 256 lane-pairs
#define NBK 782              // dst buckets of 256 nodes (782*256 >= 200000)
#define BW 256               // nodes per bucket (dl fits 8 bits)
#define CAP 9984             // edges counting-sorted per chunk in agg1 (39.9 KB LDS)
#define CHUNK 6144           // edges per binning block -> 1042 blocks, 47.3 KB LDS (3/CU)

// ---------- bucket build ----------

__global__ void k_zero_i(int* __restrict__ p, int n) {
  int i = blockIdx.x * blockDim.x + threadIdx.x;
  if (i < n) p[i] = 0;
}

// per-block histogram -> blockhist row (persisted) + global bucket counts
__global__ void k_hist(const int* __restrict__ dst, int e, int* __restrict__ gcnt,
                       int* __restrict__ blockhist) {
  __shared__ int h[NBK];
  for (int i = threadIdx.x; i < NBK; i += BLK) h[i] = 0;
  __syncthreads();
  int base = blockIdx.x * CHUNK;
  int m = min(CHUNK, e - base);
  for (int k = threadIdx.x; k < m; k += BLK) atomicAdd(&h[dst[base + k] >> 8], 1);
  __syncthreads();
  int* row = blockhist + (size_t)blockIdx.x * NBK;
  for (int b = threadIdx.x; b < NBK; b += BLK) {
    int c = h[b];
    row[b] = c;
    if (c) atomicAdd(&gcnt[b], c);
  }
}

// exclusive scan of gcnt[NBK] -> gbase[NBK+1]; init gcur. single block, 1024 thr.
__global__ void k_scan(const int* __restrict__ gcnt, int* __restrict__ gbase,
                       int* __restrict__ gcur, int e) {
  __shared__ int s[1024];
  int t = threadIdx.x;
  int v = (t < NBK) ? gcnt[t] : 0;
  s[t] = v;
  __syncthreads();
  for (int d = 1; d < 1024; d <<= 1) {
    int u = (t >= d) ? s[t - d] : 0;
    __syncthreads();
    s[t] += u;
    __syncthreads();
  }
  if (t < NBK) { int ex = s[t] - v; gbase[t] = ex; gcur[t] = ex; }
  if (t == 0) gbase[NBK] = e;
}

// bin edges: load saved histogram, LDS counting-sort, coalesced write-out with
// direct pos->bucket lookup (bkt16) instead of binary search.
__global__ void __launch_bounds__(BLK) k_bin(const int* __restrict__ src,
                                             const int* __restrict__ dst, int e,
                                             int* __restrict__ gcur,
                                             const int* __restrict__ blockhist,
                                             unsigned* __restrict__ binned) {
  __shared__ int lcnt[NBK];        // histogram, then reused as scatter cursor
  __shared__ int loff[NBK + 1];
  __shared__ int lbase[NBK];
  __shared__ int part[BLK];
  __shared__ unsigned sorted[CHUNK];        // 24 KB
  __shared__ unsigned short bkt16[CHUNK];   // 12 KB
  int t = threadIdx.x;
  int base = blockIdx.x * CHUNK;
  int m = min(CHUNK, e - base);

  // 1. load this block's histogram (coalesced 3 KB)
  const int* row = blockhist + (size_t)blockIdx.x * NBK;
  for (int i = t; i < NBK; i += BLK) lcnt[i] = row[i];
  __syncthreads();
  // 2. exclusive scan over 782 bins (4 bins/thread + Hillis-Steele over 256 partials)
  int b0 = 4 * t;
  int s0 = (b0 + 0 < NBK) ? lcnt[b0 + 0] : 0;
  int s1 = (b0 + 1 < NBK) ? lcnt[b0 + 1] : 0;
  int s2 = (b0 + 2 < NBK) ? lcnt[b0 + 2] : 0;
  int s3 = (b0 + 3 < NBK) ? lcnt[b0 + 3] : 0;
  int tsum = s0 + s1 + s2 + s3;
  part[t] = tsum;
  __syncthreads();
  for (int d = 1; d < BLK; d <<= 1) {
    int u = (t >= d) ? part[t - d] : 0;
    __syncthreads();
    part[t] += u;
    __syncthreads();
  }
  int ex = part[t] - tsum;
  if (b0 + 0 < NBK) loff[b0 + 0] = ex;
  if (b0 + 1 < NBK) loff[b0 + 1] = ex + s0;
  if (b0 + 2 < NBK) loff[b0 + 2] = ex + s0 + s1;
  if (b0 + 3 < NBK) loff[b0 + 3] = ex + s0 + s1 + s2;
  if (t == 0) loff[NBK] = m;
  __syncthreads();
  // 3. reserve global windows; convert lcnt into scatter cursor
  for (int b = t; b < NBK; b += BLK) {
    int c = lcnt[b];
    lbase[b] = c ? atomicAdd(&gcur[b], c) : 0;
  }
  __syncthreads();
  for (int b = t; b < NBK; b += BLK) lcnt[b] = loff[b];
  __syncthreads();
  // 4. scatter into LDS sorted order (single pass over edges)
  for (int k = t; k < m; k += BLK) {
    int d = dst[base + k];
    int b = d >> 8;
    int dl = d & 255;
    int pos = atomicAdd(&lcnt[b], 1);
    sorted[pos] = (unsigned)src[base + k] | ((unsigned)dl << 18);
    bkt16[pos] = (unsigned short)b;
  }
  __syncthreads();
  // 5. coalesced write-out: direct lookup
  for (int i = t; i < m; i += BLK) {
    int b = bkt16[i];
    binned[lbase[b] + (i - loff[b])] = sorted[i];
  }
}

// fused: per-bucket degree -> dinv -> hs1 = fp16( (x @ W1) * dinv )
__global__ void k_ldeg_t1(const unsigned* __restrict__ binned, const int* __restrict__ gbase,
                          const float* __restrict__ x, const float* __restrict__ W1,
                          float* __restrict__ dinv, __half* __restrict__ hs1, int n) {
  __shared__ int cnt[BW];
  __shared__ float w[160];
  int t = threadIdx.x;
  cnt[t] = 0;
  if (t < 160) w[t] = W1[t];
  __syncthreads();
  int b = blockIdx.x;
  int p0 = gbase[b], p1 = gbase[b + 1];
  for (int p = p0 + t; p < p1; p += BLK) atomicAdd(&cnt[binned[p] >> 18], 1);
  __syncthreads();
  int v = b * BW + t;
  if (v >= n) return;
  float di = rsqrtf((float)cnt[t] + 1.0f);
  dinv[v] = di;
  float xi[10];
#pragma unroll
  for (int k = 0; k < 10; k++) xi[k] = x[(size_t)v * 10 + k];
  __half2 hv[8];
#pragma unroll
  for (int j = 0; j < 8; j++) {
    float acc0 = 0.f, acc1 = 0.f;
#pragma unroll
    for (int k = 0; k < 10; k++) {
      acc0 = fmaf(xi[k], w[k * 16 + 2 * j], acc0);
      acc1 = fmaf(xi[k], w[k * 16 + 2 * j + 1], acc1);
    }
    hv[j] = __floats2half2_rn(acc0 * di, acc1 * di);
  }
  float4* o = (float4*)(hs1 + (size_t)v * 16);
  o[0] = *(float4*)&hv[0];
  o[1] = *(float4*)&hv[4];
}

// layer-1 aggregation, zero float atomics: counting-sort by dl in LDS, lane-pair register
// accumulate, fused layer-2 epilogue.
__global__ void __launch_bounds__(ABLK) k_agg1s(const unsigned* __restrict__ binned,
                                                const int* __restrict__ gbase,
                                                const __half* __restrict__ hs1,
                                                const float* __restrict__ dinv,
                                                const float* __restrict__ b1,
                                                const float* __restrict__ W2,
                                                float* __restrict__ hs2, int n) {
  __shared__ int cnt[BW];
  __shared__ int stmp[BW];
  __shared__ int off[BW + 1];
  __shared__ int cur[BW];
  __shared__ int sorted[CAP];
  __shared__ float w2[32];
  __shared__ float sb1[16];
  int t = threadIdx.x;
  if (t < 32) w2[t] = W2[t];
  if (t >= 32 && t < 48) sb1[t - 32] = b1[t - 32];
  int bkt = blockIdx.x;
  int p0 = gbase[bkt], p1 = gbase[bkt + 1];
  const int j = t >> 1;
  const int c = t & 1;
  float acc[8];
#pragma unroll
  for (int q = 0; q < 8; q++) acc[q] = 0.f;

#define ACCR(R) { const __half2* h2_ = (const __half2*)&R; \
    float2 f0_ = __half22float2(h2_[0]); \
    float2 f1_ = __half22float2(h2_[1]); \
    float2 f2_ = __half22float2(h2_[2]); \
    float2 f3_ = __half22float2(h2_[3]); \
    acc[0] += f0_.x; acc[1] += f0_.y; acc[2] += f1_.x; acc[3] += f1_.y; \
    acc[4] += f2_.x; acc[5] += f2_.y; acc[6] += f3_.x; acc[7] += f3_.y; }

  int p = p0;
  while (p < p1) {
    int m = min(CAP, p1 - p);
    if (t < BW) cnt[t] = 0;
    __syncthreads();
    for (int i = t; i < m; i += ABLK) atomicAdd(&cnt[binned[p + i] >> 18], 1);
    __syncthreads();
    if (t < BW) stmp[t] = cnt[t];
    __syncthreads();
    for (int d = 1; d < BW; d <<= 1) {
      int u = 0;
      if (t < BW && t >= d) u = stmp[t - d];
      __syncthreads();
      if (t < BW) stmp[t] += u;
      __syncthreads();
    }
    if (t < BW) { int ex = stmp[t] - cnt[t]; off[t] = ex; cur[t] = ex; }
    if (t == 0) off[BW] = m;
    __syncthreads();
    for (int i = t; i < m; i += ABLK) {
      unsigned pk = binned[p + i];
      int pos = atomicAdd(&cur[pk >> 18], 1);
      sorted[pos] = (int)(pk & 0x3FFFF);
    }
    __syncthreads();
    int i0 = off[j], i1 = off[j + 1];
    int i = i0;
    for (; i + 3 < i1; i += 4) {
      int s0 = sorted[i + 0];
      int s1 = sorted[i + 1];
      int s2 = sorted[i + 2];
      int s3 = sorted[i + 3];
      float4 r0 = *(const float4*)(hs1 + (size_t)s0 * 16 + c * 8);
      float4 r1 = *(const float4*)(hs1 + (size_t)s1 * 16 + c * 8);
      float4 r2 = *(const float4*)(hs1 + (size_t)s2 * 16 + c * 8);
      float4 r3 = *(const float4*)(hs1 + (size_t)s3 * 16 + c * 8);
      ACCR(r0); ACCR(r1); ACCR(r2); ACCR(r3);
    }
    for (; i < i1; i++) {
      int s = sorted[i];
      float4 r = *(const float4*)(hs1 + (size_t)s * 16 + c * 8);
      ACCR(r);
    }
    __syncthreads();
    p += m;
  }
#undef ACCR

  int v = bkt * BW + j;
  if (v < n) {
    float di = dinv[v];
    float4 sf = *(const float4*)(hs1 + (size_t)v * 16 + c * 8);
    const __half2* sh = (const __half2*)&sf;
    float h0c = 0.f, h1c = 0.f;
#pragma unroll
    for (int q = 0; q < 4; q++) {
      float2 sv = __half22float2(sh[q]);
      int f0 = c * 8 + 2 * q;
      int f1 = f0 + 1;
      float a0 = fmaxf(fmaf(di, acc[2 * q + 0] + sv.x, sb1[f0]), 0.f);
      float a1 = fmaxf(fmaf(di, acc[2 * q + 1] + sv.y, sb1[f1]), 0.f);
      h0c = fmaf(a0, w2[f0 * 2 + 0], fmaf(a1, w2[f1 * 2 + 0], h0c));
      h1c = fmaf(a0, w2[f0 * 2 + 1], fmaf(a1, w2[f1 * 2 + 1], h1c));
    }
    float h0 = h0c + __shfl_xor(h0c, 1);
    float h1 = h1c + __shfl_xor(h1c, 1);
    if (c == 0) {
      hs2[(size_t)v * 2 + 0] = h0 * di;
      hs2[(size_t)v * 2 + 1] = h1 * di;
    }
  }
}

// layer-2 aggregate + output; hs2 = 1.6 MB L2-resident. LDS pad stride 3.
__global__ void k_agg2(const unsigned* __restrict__ binned, const int* __restrict__ gbase,
                       const float* __restrict__ hs2, const float* __restrict__ dinv,
                       const float* __restrict__ b2, float* __restrict__ out, int n) {
  __shared__ float agg[BW * 3];
  int t = threadIdx.x;
  for (int i = t; i < BW * 3; i += BLK) agg[i] = 0.f;
  __syncthreads();
  int bkt = blockIdx.x;
  int p0 = gbase[bkt], p1 = gbase[bkt + 1];
  int p = p0 + t;
#define ACC2(pk, M) { int dl_ = (pk) >> 18; \
    atomicAdd(&agg[dl_ * 3 + 0], M.x); atomicAdd(&agg[dl_ * 3 + 1], M.y); }
  for (; p + 3 * BLK < p1; p += 4 * BLK) {
    unsigned pk0 = binned[p];
    unsigned pk1 = binned[p + BLK];
    unsigned pk2 = binned[p + 2 * BLK];
    unsigned pk3 = binned[p + 3 * BLK];
    float2 m0 = *(const float2*)(hs2 + (size_t)(pk0 & 0x3FFFF) * 2);
    float2 m1 = *(const float2*)(hs2 + (size_t)(pk1 & 0x3FFFF) * 2);
    float2 m2 = *(const float2*)(hs2 + (size_t)(pk2 & 0x3FFFF) * 2);
    float2 m3 = *(const float2*)(hs2 + (size_t)(pk3 & 0x3FFFF) * 2);
    ACC2(pk0, m0); ACC2(pk1, m1); ACC2(pk2, m2); ACC2(pk3, m3);
  }
  for (; p < p1; p += BLK) {
    unsigned pk = binned[p];
    float2 m = *(const float2*)(hs2 + (size_t)(pk & 0x3FFFF) * 2);
    ACC2(pk, m);
  }
#undef ACC2
  __syncthreads();
  int v = bkt * BW + t;
  if (v < n) {
    float di = dinv[v];
    out[(size_t)v * 2 + 0] = fmaf(di, agg[t * 3 + 0] + hs2[(size_t)v * 2 + 0], b2[0]);
    out[(size_t)v * 2 + 1] = fmaf(di, agg[t * 3 + 1] + hs2[(size_t)v * 2 + 1], b2[1]);
  }
}

extern "C" void kernel_launch(void* const* d_in, const int* in_sizes, int n_in,
                              void* d_out, int out_size, void* d_ws, size_t ws_size,
                              hipStream_t stream) {
  const float* x  = (const float*)d_in[0];
  const int*   ei = (const int*)d_in[1];
  const float* W1 = (const float*)d_in[2];
  const float* b1 = (const float*)d_in[3];
  const float* W2 = (const float*)d_in[4];
  const float* b2 = (const float*)d_in[5];
  float* out = (float*)d_out;

  const int n = in_sizes[0] / 10;   // 200000
  const int e = in_sizes[1] / 2;    // 6400000
  const int* src = ei;
  const int* dst = ei + e;

  int gC = (e + CHUNK - 1) / CHUNK;   // 1042 binning blocks

  // workspace layout (~38 MB)
  char* ws = (char*)d_ws;
  int*      gcnt      = (int*)ws;      ws += (size_t)NBK * 4;
  int*      gbase     = (int*)ws;      ws += ((size_t)NBK + 1) * 4;
  int*      gcur      = (int*)ws;      ws += (size_t)NBK * 4;
  int*      blockhist = (int*)ws;      ws += (size_t)gC * NBK * 4;
  unsigned* binned    = (unsigned*)ws; ws += (size_t)e * 4;
  float*    dinv      = (float*)ws;    ws += (size_t)n * 4;
  __half*   hs1       = (__half*)ws;   ws += (size_t)n * 16 * 2;
  float*    hs2       = (float*)ws;    ws += (size_t)n * 2 * 4;

  k_zero_i<<<(NBK + BLK - 1) / BLK, BLK, 0, stream>>>(gcnt, NBK);
  k_hist<<<gC, BLK, 0, stream>>>(dst, e, gcnt, blockhist);
  k_scan<<<1, 1024, 0, stream>>>(gcnt, gbase, gcur, e);
  k_bin<<<gC, BLK, 0, stream>>>(src, dst, e, gcur, blockhist, binned);
  k_ldeg_t1<<<NBK, BLK, 0, stream>>>(binned, gbase, x, W1, dinv, hs1, n);
  k_agg1s<<<NBK, ABLK, 0, stream>>>(binned, gbase, hs1, dinv, b1, W2, hs2, n);
  k_agg2<<<NBK, BLK, 0, stream>>>(binned, gbase, hs2, dinv, b2, out, n);
}

// Round 12
// 372.253 us; speedup vs baseline: 2.5454x; 1.0557x over previous
//
#include <hip/hip_runtime.h>
#include <hip/hip_fp16.h>

#define BLK 256
#define BBLK 512             // k_bin block (2x waves for latency hiding)
#define ABLK 512             // agg1 block: 256 lane-pairs
#define NBK 782              // dst buckets of 256 nodes (782*256 >= 200000)
#define BW 256               // nodes per bucket (dl fits 8 bits)
#define CAP 9984             // edges counting-sorted per chunk in agg1 (39.9 KB LDS)
#define CHUNK 6144           // edges per binning block -> 1042 blocks, 47.2 KB LDS (3/CU)

// ---------- bucket build ----------

__global__ void k_zero_i(int* __restrict__ p, int n) {
  int i = blockIdx.x * blockDim.x + threadIdx.x;
  if (i < n) p[i] = 0;
}

// per-block histogram -> blockhist row (persisted) + global bucket counts
__global__ void k_hist(const int* __restrict__ dst, int e, int* __restrict__ gcnt,
                       int* __restrict__ blockhist) {
  __shared__ int h[NBK];
  for (int i = threadIdx.x; i < NBK; i += BLK) h[i] = 0;
  __syncthreads();
  int base = blockIdx.x * CHUNK;
  int m = min(CHUNK, e - base);
  for (int k = threadIdx.x; k < m; k += BLK) atomicAdd(&h[dst[base + k] >> 8], 1);
  __syncthreads();
  int* row = blockhist + (size_t)blockIdx.x * NBK;
  for (int b = threadIdx.x; b < NBK; b += BLK) {
    int c = h[b];
    row[b] = c;
    if (c) atomicAdd(&gcnt[b], c);
  }
}

// exclusive scan of gcnt[NBK] -> gbase[NBK+1]; init gcur. single block, 1024 thr.
__global__ void k_scan(const int* __restrict__ gcnt, int* __restrict__ gbase,
                       int* __restrict__ gcur, int e) {
  __shared__ int s[1024];
  int t = threadIdx.x;
  int v = (t < NBK) ? gcnt[t] : 0;
  s[t] = v;
  __syncthreads();
  for (int d = 1; d < 1024; d <<= 1) {
    int u = (t >= d) ? s[t - d] : 0;
    __syncthreads();
    s[t] += u;
    __syncthreads();
  }
  if (t < NBK) { int ex = s[t] - v; gbase[t] = ex; gcur[t] = ex; }
  if (t == 0) gbase[NBK] = e;
}

// bin edges: load saved histogram, LDS counting-sort, coalesced write-out with
// direct pos->bucket lookup. BBLK=512 (24 waves/CU at 3 blocks) for latency hiding.
__global__ void __launch_bounds__(BBLK) k_bin(const int* __restrict__ src,
                                              const int* __restrict__ dst, int e,
                                              int* __restrict__ gcur,
                                              const int* __restrict__ blockhist,
                                              unsigned* __restrict__ binned) {
  __shared__ int lcnt[NBK];        // histogram, then reused as scatter cursor
  __shared__ int loff[NBK + 1];
  __shared__ int lbase[NBK];
  __shared__ int part[BBLK];
  __shared__ unsigned sorted[CHUNK];        // 24 KB
  __shared__ unsigned short bkt16[CHUNK];   // 12 KB
  int t = threadIdx.x;
  int base = blockIdx.x * CHUNK;
  int m = min(CHUNK, e - base);

  // 1. load this block's histogram (coalesced 3 KB)
  const int* row = blockhist + (size_t)blockIdx.x * NBK;
  for (int i = t; i < NBK; i += BBLK) lcnt[i] = row[i];
  __syncthreads();
  // 2. exclusive scan over 782 bins (2 bins/thread + Hillis-Steele over 512 partials)
  int b0 = 2 * t;
  int s0 = (b0 + 0 < NBK) ? lcnt[b0 + 0] : 0;
  int s1 = (b0 + 1 < NBK) ? lcnt[b0 + 1] : 0;
  int tsum = s0 + s1;
  part[t] = tsum;
  __syncthreads();
  for (int d = 1; d < BBLK; d <<= 1) {
    int u = (t >= d) ? part[t - d] : 0;
    __syncthreads();
    part[t] += u;
    __syncthreads();
  }
  int ex = part[t] - tsum;
  if (b0 + 0 < NBK) loff[b0 + 0] = ex;
  if (b0 + 1 < NBK) loff[b0 + 1] = ex + s0;
  if (t == 0) loff[NBK] = m;
  __syncthreads();
  // 3. reserve global windows; convert lcnt into scatter cursor
  for (int b = t; b < NBK; b += BBLK) {
    int c = lcnt[b];
    lbase[b] = c ? atomicAdd(&gcur[b], c) : 0;
  }
  __syncthreads();
  for (int b = t; b < NBK; b += BBLK) lcnt[b] = loff[b];
  __syncthreads();
  // 4. scatter into LDS sorted order (single pass over edges)
  for (int k = t; k < m; k += BBLK) {
    int d = dst[base + k];
    int b = d >> 8;
    int dl = d & 255;
    int pos = atomicAdd(&lcnt[b], 1);
    sorted[pos] = (unsigned)src[base + k] | ((unsigned)dl << 18);
    bkt16[pos] = (unsigned short)b;
  }
  __syncthreads();
  // 5. coalesced write-out: direct lookup
  for (int i = t; i < m; i += BBLK) {
    int b = bkt16[i];
    binned[lbase[b] + (i - loff[b])] = sorted[i];
  }
}

// fused: per-bucket degree -> dinv -> hs1 = fp16( (x @ W1) * dinv )
__global__ void k_ldeg_t1(const unsigned* __restrict__ binned, const int* __restrict__ gbase,
                          const float* __restrict__ x, const float* __restrict__ W1,
                          float* __restrict__ dinv, __half* __restrict__ hs1, int n) {
  __shared__ int cnt[BW];
  __shared__ float w[160];
  int t = threadIdx.x;
  cnt[t] = 0;
  if (t < 160) w[t] = W1[t];
  __syncthreads();
  int b = blockIdx.x;
  int p0 = gbase[b], p1 = gbase[b + 1];
  for (int p = p0 + t; p < p1; p += BLK) atomicAdd(&cnt[binned[p] >> 18], 1);
  __syncthreads();
  int v = b * BW + t;
  if (v >= n) return;
  float di = rsqrtf((float)cnt[t] + 1.0f);
  dinv[v] = di;
  float xi[10];
#pragma unroll
  for (int k = 0; k < 10; k++) xi[k] = x[(size_t)v * 10 + k];
  __half2 hv[8];
#pragma unroll
  for (int j = 0; j < 8; j++) {
    float acc0 = 0.f, acc1 = 0.f;
#pragma unroll
    for (int k = 0; k < 10; k++) {
      acc0 = fmaf(xi[k], w[k * 16 + 2 * j], acc0);
      acc1 = fmaf(xi[k], w[k * 16 + 2 * j + 1], acc1);
    }
    hv[j] = __floats2half2_rn(acc0 * di, acc1 * di);
  }
  float4* o = (float4*)(hs1 + (size_t)v * 16);
  o[0] = *(float4*)&hv[0];
  o[1] = *(float4*)&hv[4];
}

// layer-1 aggregation, zero float atomics: counting-sort by dl in LDS, lane-pair register
// accumulate, fused layer-2 epilogue.
__global__ void __launch_bounds__(ABLK) k_agg1s(const unsigned* __restrict__ binned,
                                                const int* __restrict__ gbase,
                                                const __half* __restrict__ hs1,
                                                const float* __restrict__ dinv,
                                                const float* __restrict__ b1,
                                                const float* __restrict__ W2,
                                                float* __restrict__ hs2, int n) {
  __shared__ int cnt[BW];
  __shared__ int stmp[BW];
  __shared__ int off[BW + 1];
  __shared__ int cur[BW];
  __shared__ int sorted[CAP];
  __shared__ float w2[32];
  __shared__ float sb1[16];
  int t = threadIdx.x;
  if (t < 32) w2[t] = W2[t];
  if (t >= 32 && t < 48) sb1[t - 32] = b1[t - 32];
  int bkt = blockIdx.x;
  int p0 = gbase[bkt], p1 = gbase[bkt + 1];
  const int j = t >> 1;
  const int c = t & 1;
  float acc[8];
#pragma unroll
  for (int q = 0; q < 8; q++) acc[q] = 0.f;

#define ACCR(R) { const __half2* h2_ = (const __half2*)&R; \
    float2 f0_ = __half22float2(h2_[0]); \
    float2 f1_ = __half22float2(h2_[1]); \
    float2 f2_ = __half22float2(h2_[2]); \
    float2 f3_ = __half22float2(h2_[3]); \
    acc[0] += f0_.x; acc[1] += f0_.y; acc[2] += f1_.x; acc[3] += f1_.y; \
    acc[4] += f2_.x; acc[5] += f2_.y; acc[6] += f3_.x; acc[7] += f3_.y; }

  int p = p0;
  while (p < p1) {
    int m = min(CAP, p1 - p);
    if (t < BW) cnt[t] = 0;
    __syncthreads();
    for (int i = t; i < m; i += ABLK) atomicAdd(&cnt[binned[p + i] >> 18], 1);
    __syncthreads();
    if (t < BW) stmp[t] = cnt[t];
    __syncthreads();
    for (int d = 1; d < BW; d <<= 1) {
      int u = 0;
      if (t < BW && t >= d) u = stmp[t - d];
      __syncthreads();
      if (t < BW) stmp[t] += u;
      __syncthreads();
    }
    if (t < BW) { int ex = stmp[t] - cnt[t]; off[t] = ex; cur[t] = ex; }
    if (t == 0) off[BW] = m;
    __syncthreads();
    for (int i = t; i < m; i += ABLK) {
      unsigned pk = binned[p + i];
      int pos = atomicAdd(&cur[pk >> 18], 1);
      sorted[pos] = (int)(pk & 0x3FFFF);
    }
    __syncthreads();
    int i0 = off[j], i1 = off[j + 1];
    int i = i0;
    for (; i + 3 < i1; i += 4) {
      int s0 = sorted[i + 0];
      int s1 = sorted[i + 1];
      int s2 = sorted[i + 2];
      int s3 = sorted[i + 3];
      float4 r0 = *(const float4*)(hs1 + (size_t)s0 * 16 + c * 8);
      float4 r1 = *(const float4*)(hs1 + (size_t)s1 * 16 + c * 8);
      float4 r2 = *(const float4*)(hs1 + (size_t)s2 * 16 + c * 8);
      float4 r3 = *(const float4*)(hs1 + (size_t)s3 * 16 + c * 8);
      ACCR(r0); ACCR(r1); ACCR(r2); ACCR(r3);
    }
    for (; i < i1; i++) {
      int s = sorted[i];
      float4 r = *(const float4*)(hs1 + (size_t)s * 16 + c * 8);
      ACCR(r);
    }
    __syncthreads();
    p += m;
  }
#undef ACCR

  int v = bkt * BW + j;
  if (v < n) {
    float di = dinv[v];
    float4 sf = *(const float4*)(hs1 + (size_t)v * 16 + c * 8);
    const __half2* sh = (const __half2*)&sf;
    float h0c = 0.f, h1c = 0.f;
#pragma unroll
    for (int q = 0; q < 4; q++) {
      float2 sv = __half22float2(sh[q]);
      int f0 = c * 8 + 2 * q;
      int f1 = f0 + 1;
      float a0 = fmaxf(fmaf(di, acc[2 * q + 0] + sv.x, sb1[f0]), 0.f);
      float a1 = fmaxf(fmaf(di, acc[2 * q + 1] + sv.y, sb1[f1]), 0.f);
      h0c = fmaf(a0, w2[f0 * 2 + 0], fmaf(a1, w2[f1 * 2 + 0], h0c));
      h1c = fmaf(a0, w2[f0 * 2 + 1], fmaf(a1, w2[f1 * 2 + 1], h1c));
    }
    float h0 = h0c + __shfl_xor(h0c, 1);
    float h1 = h1c + __shfl_xor(h1c, 1);
    if (c == 0) {
      hs2[(size_t)v * 2 + 0] = h0 * di;
      hs2[(size_t)v * 2 + 1] = h1 * di;
    }
  }
}

// layer-2 aggregate + output; hs2 = 1.6 MB L2-resident. LDS pad stride 3.
__global__ void k_agg2(const unsigned* __restrict__ binned, const int* __restrict__ gbase,
                       const float* __restrict__ hs2, const float* __restrict__ dinv,
                       const float* __restrict__ b2, float* __restrict__ out, int n) {
  __shared__ float agg[BW * 3];
  int t = threadIdx.x;
  for (int i = t; i < BW * 3; i += BLK) agg[i] = 0.f;
  __syncthreads();
  int bkt = blockIdx.x;
  int p0 = gbase[bkt], p1 = gbase[bkt + 1];
  int p = p0 + t;
#define ACC2(pk, M) { int dl_ = (pk) >> 18; \
    atomicAdd(&agg[dl_ * 3 + 0], M.x); atomicAdd(&agg[dl_ * 3 + 1], M.y); }
  for (; p + 3 * BLK < p1; p += 4 * BLK) {
    unsigned pk0 = binned[p];
    unsigned pk1 = binned[p + BLK];
    unsigned pk2 = binned[p + 2 * BLK];
    unsigned pk3 = binned[p + 3 * BLK];
    float2 m0 = *(const float2*)(hs2 + (size_t)(pk0 & 0x3FFFF) * 2);
    float2 m1 = *(const float2*)(hs2 + (size_t)(pk1 & 0x3FFFF) * 2);
    float2 m2 = *(const float2*)(hs2 + (size_t)(pk2 & 0x3FFFF) * 2);
    float2 m3 = *(const float2*)(hs2 + (size_t)(pk3 & 0x3FFFF) * 2);
    ACC2(pk0, m0); ACC2(pk1, m1); ACC2(pk2, m2); ACC2(pk3, m3);
  }
  for (; p < p1; p += BLK) {
    unsigned pk = binned[p];
    float2 m = *(const float2*)(hs2 + (size_t)(pk & 0x3FFFF) * 2);
    ACC2(pk, m);
  }
#undef ACC2
  __syncthreads();
  int v = bkt * BW + t;
  if (v < n) {
    float di = dinv[v];
    out[(size_t)v * 2 + 0] = fmaf(di, agg[t * 3 + 0] + hs2[(size_t)v * 2 + 0], b2[0]);
    out[(size_t)v * 2 + 1] = fmaf(di, agg[t * 3 + 1] + hs2[(size_t)v * 2 + 1], b2[1]);
  }
}

extern "C" void kernel_launch(void* const* d_in, const int* in_sizes, int n_in,
                              void* d_out, int out_size, void* d_ws, size_t ws_size,
                              hipStream_t stream) {
  const float* x  = (const float*)d_in[0];
  const int*   ei = (const int*)d_in[1];
  const float* W1 = (const float*)d_in[2];
  const float* b1 = (const float*)d_in[3];
  const float* W2 = (const float*)d_in[4];
  const float* b2 = (const float*)d_in[5];
  float* out = (float*)d_out;

  const int n = in_sizes[0] / 10;   // 200000
  const int e = in_sizes[1] / 2;    // 6400000
  const int* src = ei;
  const int* dst = ei + e;

  int gC = (e + CHUNK - 1) / CHUNK;   // 1042 binning blocks

  // workspace layout (~38 MB)
  char* ws = (char*)d_ws;
  int*      gcnt      = (int*)ws;      ws += (size_t)NBK * 4;
  int*      gbase     = (int*)ws;      ws += ((size_t)NBK + 1) * 4;
  int*      gcur      = (int*)ws;      ws += (size_t)NBK * 4;
  int*      blockhist = (int*)ws;      ws += (size_t)gC * NBK * 4;
  unsigned* binned    = (unsigned*)ws; ws += (size_t)e * 4;
  float*    dinv      = (float*)ws;    ws += (size_t)n * 4;
  __half*   hs1       = (__half*)ws;   ws += (size_t)n * 16 * 2;
  float*    hs2       = (float*)ws;    ws += (size_t)n * 2 * 4;

  k_zero_i<<<(NBK + BLK - 1) / BLK, BLK, 0, stream>>>(gcnt, NBK);
  k_hist<<<gC, BLK, 0, stream>>>(dst, e, gcnt, blockhist);
  k_scan<<<1, 1024, 0, stream>>>(gcnt, gbase, gcur, e);
  k_bin<<<gC, BBLK, 0, stream>>>(src, dst, e, gcur, blockhist, binned);
  k_ldeg_t1<<<NBK, BLK, 0, stream>>>(binned, gbase, x, W1, dinv, hs1, n);
  k_agg1s<<<NBK, ABLK, 0, stream>>>(binned, gbase, hs1, dinv, b1, W2, hs2, n);
  k_agg2<<<NBK, BLK, 0, stream>>>(binned, gbase, hs2, dinv, b2, out, n);
}